// Round 1
// baseline (2926.826 us; speedup 1.0000x reference)
//
#include <hip/hip_runtime.h>
#include <hip/hip_bf16.h>

// ---------------- problem constants ----------------
#define Bn   4
#define Lq   1024
#define Dm   768
#define Mm   48
#define NEe  24
#define Pp   552          // NE*(NE-1)
#define Ee   576          // P + NE (self loops)
#define Hh   12
#define BSz  64
#define Rr   97
#define Nn   2208         // B*P
#define NEG_SLOPE 0.2f

// ============================================================
// entity[b,n,d] = log( sum_m emap[b,n,m] * exp(ctx[b, mmap[b,m], d]) )
// grid: B*NE blocks, 256 threads
__global__ void k_entity(const float* __restrict__ ctx, const int* __restrict__ mmap,
                         const float* __restrict__ emap, float* __restrict__ entity)
{
    int x = blockIdx.x;              // b*NE + n
    int b = x / NEe;
    int rows[8]; float wts[8]; int nnz = 0;
    for (int m = 0; m < Mm; ++m) {
        float w = emap[(long)x * Mm + m];
        if (w != 0.f && nnz < 8) { rows[nnz] = mmap[b * Mm + m]; wts[nnz] = w; ++nnz; }
    }
    const float* cbase = ctx + (long)b * Lq * Dm;
    for (int d = threadIdx.x; d < Dm; d += 256) {
        float s = 0.f;
        for (int z = 0; z < nnz; ++z) s += wts[z] * expf(cbase[(long)rows[z] * Dm + d]);
        entity[(long)x * Dm + d] = logf(s);
    }
}

// cur[b,h,n,l] = (sum_m emap*att[b,h,mmap[b,m],l]) / (cnt[b,n] + 1e-20)
// grid: B*H*NE blocks, 256 threads
__global__ void k_cur(const float* __restrict__ att, const int* __restrict__ mmap,
                      const float* __restrict__ emap, float* __restrict__ cur)
{
    int x = blockIdx.x;
    int b = x / (Hh * NEe); int rem = x % (Hh * NEe);
    int h = rem / NEe;      int n = rem % NEe;
    float cnt = 0.f;
    int rows[8]; float wts[8]; int nnz = 0;
    for (int m = 0; m < Mm; ++m) {
        float w = emap[((long)b * NEe + n) * Mm + m];
        cnt += w;
        if (w != 0.f && nnz < 8) { rows[nnz] = mmap[b * Mm + m]; wts[nnz] = w; ++nnz; }
    }
    float inv = 1.f / (cnt + 1e-20f);
    const float* abase = att + ((long)b * Hh + h) * (long)Lq * Lq;
    float* obase = cur + (long)x * Lq;
    for (int l = threadIdx.x; l < Lq; l += 256) {
        float s = 0.f;
        for (int z = 0; z < nnz; ++z) s += wts[z] * abase[(long)rows[z] * Lq + l];
        obase[l] = s * inv;
    }
}

// ca[b,p,l] = sum_h cur[b,h,h0,l]*cur[b,h,h1,l], then row-normalize over l
// grid: B*P blocks, 256 threads
__global__ void k_ca(const float* __restrict__ cur, const int* __restrict__ hts,
                     float* __restrict__ ca)
{
    int bp = blockIdx.x; int b = bp / Pp, p = bp % Pp;
    int n0 = hts[p], n1 = hts[Pp + p];
    __shared__ float red[256];
    float vals[4]; float lsum = 0.f;
    for (int t = 0; t < 4; ++t) {
        int l = threadIdx.x + t * 256;
        float v = 0.f;
        #pragma unroll
        for (int h = 0; h < Hh; ++h) {
            v += cur[(((long)b * Hh + h) * NEe + n0) * Lq + l] *
                 cur[(((long)b * Hh + h) * NEe + n1) * Lq + l];
        }
        vals[t] = v; lsum += v;
    }
    red[threadIdx.x] = lsum; __syncthreads();
    for (int s = 128; s > 0; s >>= 1) {
        if (threadIdx.x < s) red[threadIdx.x] += red[threadIdx.x + s];
        __syncthreads();
    }
    float inv = 1.f / (red[0] + 1e-20f);
    for (int t = 0; t < 4; ++t) {
        int l = threadIdx.x + t * 256;
        ca[(long)bp * Lq + l] = vals[t] * inv;
    }
}

// generic tiled f32 GEMM: C = act(A[M,K] @ W[K,N] + bias), row-major, N%64==0, K%16==0
// grid: (N/64, ceil(M/64), batch), 256 threads
__global__ __launch_bounds__(256)
void k_gemm(const float* __restrict__ A, const float* __restrict__ W,
            const float* __restrict__ bias, float* __restrict__ C,
            int M, int N, int K, long sA, long sW, long sC, int act)
{
    A += (long)blockIdx.z * sA;
    W += (long)blockIdx.z * sW;
    C += (long)blockIdx.z * sC;
    __shared__ float As[16][68];
    __shared__ float Ws[16][68];
    const int tid = threadIdx.x;
    const int tx = tid & 15, ty = tid >> 4;
    const int row0 = blockIdx.y * 64, col0 = blockIdx.x * 64;
    float acc[4][4] = {};
    for (int k0 = 0; k0 < K; k0 += 16) {
        #pragma unroll
        for (int s = 0; s < 4; ++s) {
            int idx = tid + s * 256;
            int r = idx >> 4, kk = idx & 15;
            int gr = row0 + r;
            As[kk][r] = (gr < M) ? A[(long)gr * K + k0 + kk] : 0.f;
        }
        #pragma unroll
        for (int s = 0; s < 4; ++s) {
            int idx = tid + s * 256;
            int kk = idx >> 6, cc = idx & 63;
            Ws[kk][cc] = W[(long)(k0 + kk) * N + col0 + cc];
        }
        __syncthreads();
        #pragma unroll
        for (int kk = 0; kk < 16; ++kk) {
            float w0 = Ws[kk][tx * 4 + 0], w1 = Ws[kk][tx * 4 + 1];
            float w2 = Ws[kk][tx * 4 + 2], w3 = Ws[kk][tx * 4 + 3];
            #pragma unroll
            for (int i2 = 0; i2 < 4; ++i2) {
                float av = As[kk][ty * 4 + i2];
                acc[i2][0] += av * w0; acc[i2][1] += av * w1;
                acc[i2][2] += av * w2; acc[i2][3] += av * w3;
            }
        }
        __syncthreads();
    }
    #pragma unroll
    for (int i2 = 0; i2 < 4; ++i2) {
        int gr = row0 + ty * 4 + i2;
        if (gr >= M) continue;
        #pragma unroll
        for (int j2 = 0; j2 < 4; ++j2) {
            int gc = col0 + tx * 4 + j2;
            float v = acc[i2][j2] + (bias ? bias[gc] : 0.f);
            if (act) v = tanhf(v);
            C[(long)gr * N + gc] = v;
        }
    }
}

// cat rows: out[g][0:768] = nodes[b, sel[p]]; out[g][768:1536] = feat[g]
// grid: Nn blocks, 256 threads
__global__ void k_cat(const float* __restrict__ nodes, const float* __restrict__ feat,
                      const int* __restrict__ sel, float* __restrict__ out)
{
    int g = blockIdx.x; int b = g / Pp, p = g % Pp;
    int nidx = sel[p];
    const float* nb = nodes + ((long)b * NEe + nidx) * Dm;
    const float* fb = feat + (long)g * Dm;
    float* ob = out + (long)g * 2 * Dm;
    for (int d = threadIdx.x; d < Dm; d += 256) {
        ob[d] = nb[d];
        ob[Dm + d] = fb[d];
    }
}

// blockwise bilinear: part[h][n][o] = sum_{i,j} a[n,h,i]*c[n,h,j]*W[((h*64+i)*64+j), o]
// grid: (ceil(Nn/128), Hh), 256 threads (32 row-groups x 8 col-threads, 4 rows each)
template<int RR>
__global__ __launch_bounds__(256)
void k_gbl(const float* __restrict__ Aact, const float* __restrict__ Cact,
           const float* __restrict__ W, float* __restrict__ part)
{
    __shared__ float a_s[128][65];
    __shared__ float c_s[128][65];
    const int h = blockIdx.y;
    const int row0 = blockIdx.x * 128;
    const int tid = threadIdx.x;
    const int rg = tid >> 3;        // 0..31
    const int c  = tid & 7;
    const int r0l = rg * 4;
    #pragma unroll
    for (int s = 0; s < 32; ++s) {
        int idx = tid + s * 256;     // 0..8191
        int r = idx >> 6, col = idx & 63;
        int gr = row0 + r;
        float av = 0.f, cv = 0.f;
        if (gr < Nn) {
            av = Aact[(long)gr * Dm + h * BSz + col];
            cv = Cact[(long)gr * Dm + h * BSz + col];
        }
        a_s[r][col] = av;
        c_s[r][col] = cv;
    }
    __syncthreads();
    constexpr int NC = (RR + 7) / 8;
    float acc[4][NC];
    #pragma unroll
    for (int k = 0; k < 4; ++k)
        #pragma unroll
        for (int m = 0; m < NC; ++m) acc[k][m] = 0.f;

    for (int i = 0; i < BSz; ++i) {
        float av0 = a_s[r0l + 0][i], av1 = a_s[r0l + 1][i];
        float av2 = a_s[r0l + 2][i], av3 = a_s[r0l + 3][i];
        const float* wrow = W + ((long)(h * BSz + i) * BSz) * RR;
        for (int j = 0; j < BSz; ++j) {
            float cv0 = c_s[r0l + 0][j], cv1 = c_s[r0l + 1][j];
            float cv2 = c_s[r0l + 2][j], cv3 = c_s[r0l + 3][j];
            float f0 = av0 * cv0, f1 = av1 * cv1, f2 = av2 * cv2, f3 = av3 * cv3;
            const float* wj = wrow + (long)j * RR;
            #pragma unroll
            for (int m = 0; m < NC; ++m) {
                int o = c + 8 * m;
                if (o < RR) {
                    float wv = wj[o];
                    acc[0][m] += f0 * wv; acc[1][m] += f1 * wv;
                    acc[2][m] += f2 * wv; acc[3][m] += f3 * wv;
                }
            }
        }
    }
    #pragma unroll
    for (int k = 0; k < 4; ++k) {
        int gr = row0 + r0l + k;
        if (gr < Nn) {
            #pragma unroll
            for (int m = 0; m < NC; ++m) {
                int o = c + 8 * m;
                if (o < RR) part[((long)h * Nn + gr) * RR + o] = acc[k][m];
            }
        }
    }
}

// out[n*RR+o] = bias[o] + sum_h part[h][n][o]
__global__ void k_gbl_reduce(const float* __restrict__ part, const float* __restrict__ bias,
                             float* __restrict__ out, int RR, int total)
{
    int idx = blockIdx.x * 256 + threadIdx.x;
    if (idx >= total) return;
    int o = idx % RR;
    float s = bias[o];
    for (int h = 0; h < Hh; ++h) s += part[(long)h * Nn * RR + idx];
    out[idx] = s;
}

// mask[n] = bin_res[n,1] > bin_res[n,0]   (argmax==1, ties -> 0)
__global__ void k_mask(const float* __restrict__ bin, int* __restrict__ mask)
{
    int idx = blockIdx.x * 256 + threadIdx.x;
    if (idx >= Nn) return;
    mask[idx] = bin[idx * 2 + 1] > bin[idx * 2 + 0] ? 1 : 0;
}

// f_out[b,e,:] = (e<P ? fij[b,e] : 0) + ni[b,src] + nj[b,dst] + egat_b
// grid: B*E blocks, 256 threads
__global__ void k_fassemble(const float* __restrict__ fij, const float* __restrict__ ni,
                            const float* __restrict__ nj, const float* __restrict__ eb,
                            const int* __restrict__ hts, float* __restrict__ fout)
{
    int be = blockIdx.x; int b = be / Ee, e = be % Ee;
    int sn, dn; const float* fe = nullptr;
    if (e < Pp) { sn = hts[e]; dn = hts[Pp + e]; fe = fij + ((long)b * Pp + e) * Dm; }
    else        { sn = dn = e - Pp; }
    const float* nib = ni + ((long)b * NEe + sn) * Dm;
    const float* njb = nj + ((long)b * NEe + dn) * Dm;
    float* ob = fout + (long)be * Dm;
    for (int d = threadIdx.x; d < Dm; d += 256)
        ob[d] = (fe ? fe[d] : 0.f) + nib[d] + njb[d] + eb[d];
}

// score[b,e,h] = sum_j leaky_relu(f_out)*attn_p, masked -> -1e30
__global__ void k_score(const float* __restrict__ fout, const float* __restrict__ attp,
                        const int* __restrict__ mask, float* __restrict__ score)
{
    int idx = blockIdx.x * 256 + threadIdx.x;
    if (idx >= Bn * Ee * Hh) return;
    int h = idx % Hh; int be = idx / Hh; int b = be / Ee, e = be % Ee;
    const float* fb = fout + (long)be * Dm + h * BSz;
    const float* ap = attp + h * BSz;
    float s = 0.f;
    for (int j = 0; j < BSz; ++j) {
        float v = fb[j];
        float lr = v >= 0.f ? v : NEG_SLOPE * v;
        s += lr * ap[j];
    }
    bool ok = (e >= Pp) || (mask[b * Pp + e] != 0);
    score[idx] = ok ? s : -1e30f;
}

// edge softmax per (b, dst=n, h): incoming edges = {hh != n} + self loop
__global__ void k_segsoft(const float* __restrict__ score, float* __restrict__ attw)
{
    int idx = blockIdx.x * 256 + threadIdx.x;
    if (idx >= Bn * NEe * Hh) return;
    int h = idx % Hh; int bnn = idx / Hh; int b = bnn / NEe, n = bnn % NEe;
    float sc[NEe]; int es[NEe];
    float smax = -3e38f;
    #pragma unroll
    for (int hh = 0; hh < NEe; ++hh) {
        int e;
        if (hh == n) e = Pp + n;
        else         e = hh * (NEe - 1) + (n - (n > hh ? 1 : 0));
        float v = score[((long)b * Ee + e) * Hh + h];
        es[hh] = e; sc[hh] = v;
        smax = fmaxf(smax, v);
    }
    float den = 0.f;
    #pragma unroll
    for (int z = 0; z < NEe; ++z) { sc[z] = expf(sc[z] - smax); den += sc[z]; }
    float inv = 1.f / (den + 1e-20f);
    #pragma unroll
    for (int z = 0; z < NEe; ++z)
        attw[((long)b * Ee + es[z]) * Hh + h] = sc[z] * inv;
}

// node_out[b,n,d] = sum_{incoming e} hsrc[b,src(e),d] * attw[b,e,h(d)]
// grid: B*NE blocks, 256 threads
__global__ void k_nodeout(const float* __restrict__ hsrcB, const float* __restrict__ attw,
                          float* __restrict__ nout)
{
    int bnn = blockIdx.x; int b = bnn / NEe, n = bnn % NEe;
    for (int d = threadIdx.x; d < Dm; d += 256) {
        int h = d >> 6;
        float s = 0.f;
        #pragma unroll
        for (int hh = 0; hh < NEe; ++hh) {
            int e, sn;
            if (hh == n) { e = Pp + n; sn = n; }
            else         { e = hh * (NEe - 1) + (n - (n > hh ? 1 : 0)); sn = hh; }
            s += hsrcB[((long)b * NEe + sn) * Dm + d] * attw[((long)b * Ee + e) * Hh + h];
        }
        nout[(long)bnn * Dm + d] = s;
    }
}

// new_ci = mask ? f_out[:P] : ci
__global__ void k_newci(const float* __restrict__ fout, const float* __restrict__ ci,
                        const int* __restrict__ mask, float* __restrict__ newci)
{
    int idx = blockIdx.x * 256 + threadIdx.x;
    if (idx >= Nn * Dm) return;
    int n = idx / Dm, d = idx % Dm;
    int b = n / Pp, p = n % Pp;
    newci[idx] = mask[n] ? fout[((long)b * Ee + p) * Dm + d] : ci[idx];
}

// ============================================================
extern "C" void kernel_launch(void* const* d_in, const int* in_sizes, int n_in,
                              void* d_out, int out_size, void* d_ws, size_t ws_size,
                              hipStream_t stream)
{
    const float* ctx   = (const float*)d_in[0];
    const float* att   = (const float*)d_in[1];
    const int*   mmap  = (const int*)d_in[2];
    const float* emap  = (const float*)d_in[3];
    const int*   hts   = (const int*)d_in[4];
    const float* Whb   = (const float*)d_in[5];
    const float* bhb   = (const float*)d_in[6];
    const float* Wtb   = (const float*)d_in[7];
    const float* btb   = (const float*)d_in[8];
    const float* Wbin  = (const float*)d_in[9];
    const float* bbin  = (const float*)d_in[10];
    const float* Wrel  = (const float*)d_in[11];
    const float* brel  = (const float*)d_in[12];
    const float* Wh    = (const float*)d_in[13];
    const float* bh    = (const float*)d_in[14];
    const float* Wt    = (const float*)d_in[15];
    const float* bt    = (const float*)d_in[16];
    const float* Wnode = (const float*)d_in[17];
    const float* Wni   = (const float*)d_in[18];
    const float* Wfij  = (const float*)d_in[19];
    const float* Wnj   = (const float*)d_in[20];
    const float* attp  = (const float*)d_in[21];
    const float* egatb = (const float*)d_in[22];

    float* out0 = (float*)d_out;            // bin_res [2208,2]
    float* out1 = out0 + (long)Nn * 2;      // relation_res [2208,97]

    // ---- workspace layout (floats) ----
    float* w = (float*)d_ws;
    size_t off = 0;
    auto alloc = [&](size_t nf) { float* p = w + off; off += nf; return p; };
    float* entity = alloc((size_t)Bn * NEe * Dm);          // 73728
    float* curb   = alloc((size_t)Bn * Hh * NEe * Lq);     // 1179648
    float* cab    = alloc((size_t)Bn * Pp * Lq);           // 2260992
    float* cib    = alloc((size_t)Nn * Dm);                // 1695744
    float* cat1   = alloc((size_t)Nn * 2 * Dm);            // 3391488
    float* cat2   = alloc((size_t)Nn * 2 * Dm);
    float* act1   = alloc((size_t)Nn * Dm);
    float* act2   = alloc((size_t)Nn * Dm);
    float* fijb   = alloc((size_t)Nn * Dm);
    float* foutb  = alloc((size_t)Bn * Ee * Dm);           // 1769472
    float* nib    = alloc((size_t)Bn * NEe * Dm);
    float* njb    = alloc((size_t)Bn * NEe * Dm);
    float* hsrcb  = alloc((size_t)Bn * NEe * Dm);
    float* noutb  = alloc((size_t)Bn * NEe * Dm);
    float* scoreb = alloc((size_t)Bn * Ee * Hh);
    float* attwb  = alloc((size_t)Bn * Ee * Hh);
    int*   maskb  = (int*)alloc(Nn);
    // aliases (lifetimes disjoint):
    float* partb  = curb;    // [12][2208][RR<=97] = 10.3MB fits in cur+ca (13.8MB); cur/ca dead after ci
    float* newcib = fijb;    // fij dead after f_assemble

    auto gemm = [&](const float* A, const float* W_, const float* bias, float* C,
                    int M, int N, int K, int actf, int batch, long sA, long sW, long sC) {
        dim3 g(N / 64, (M + 63) / 64, batch);
        k_gemm<<<g, 256, 0, stream>>>(A, W_, bias, C, M, N, K, sA, sW, sC, actf);
    };

    // 1. entity pooling
    k_entity<<<Bn * NEe, 256, 0, stream>>>(ctx, mmap, emap, entity);
    // 2. cur
    k_cur<<<Bn * Hh * NEe, 256, 0, stream>>>(att, mmap, emap, curb);
    // 3. ca (+ normalize)
    k_ca<<<Bn * Pp, 256, 0, stream>>>(curb, hts, cab);
    // 4. ci = ca @ context (batched per b)
    gemm(cab, ctx, nullptr, cib, Pp, Dm, Lq, 0, Bn,
         (long)Pp * Lq, (long)Lq * Dm, (long)Pp * Dm);
    // 5. concat for binary head
    k_cat<<<Nn, 256, 0, stream>>>(entity, cib, hts,       cat1);
    k_cat<<<Nn, 256, 0, stream>>>(entity, cib, hts + Pp,  cat2);
    // 6. bin_h / bin_t
    gemm(cat1, Whb, bhb, act1, Nn, Dm, 2 * Dm, 1, 1, 0, 0, 0);
    gemm(cat2, Wtb, btb, act2, Nn, Dm, 2 * Dm, 1, 1, 0, 0, 0);
    // 7. binary bilinear -> out0
    k_gbl<2><<<dim3((Nn + 127) / 128, Hh), 256, 0, stream>>>(act1, act2, Wbin, partb);
    k_gbl_reduce<<<(Nn * 2 + 255) / 256, 256, 0, stream>>>(partb, bbin, out0, 2, Nn * 2);
    // 8. mask
    k_mask<<<(Nn + 255) / 256, 256, 0, stream>>>(out0, maskb);
    // 9. EGAT node linears
    gemm(entity, Wni,   nullptr, nib,   Bn * NEe, Dm, Dm, 0, 1, 0, 0, 0);
    gemm(entity, Wnj,   nullptr, njb,   Bn * NEe, Dm, Dm, 0, 1, 0, 0, 0);
    gemm(entity, Wnode, nullptr, hsrcb, Bn * NEe, Dm, Dm, 0, 1, 0, 0, 0);
    // 10. fij = ci @ Wfij
    gemm(cib, Wfij, nullptr, fijb, Nn, Dm, Dm, 0, 1, 0, 0, 0);
    // 11. f_out assembly
    k_fassemble<<<Bn * Ee, 256, 0, stream>>>(fijb, nib, njb, egatb, hts, foutb);
    // 12. scores
    k_score<<<(Bn * Ee * Hh + 255) / 256, 256, 0, stream>>>(foutb, attp, maskb, scoreb);
    // 13. edge softmax
    k_segsoft<<<(Bn * NEe * Hh + 255) / 256, 256, 0, stream>>>(scoreb, attwb);
    // 14. node aggregation
    k_nodeout<<<Bn * NEe, 256, 0, stream>>>(hsrcb, attwb, noutb);
    // 15. new_ci (NOTE: aliases fijb; fij no longer needed)
    k_newci<<<(Nn * Dm + 255) / 256, 256, 0, stream>>>(foutb, cib, maskb, newcib);
    // 16. concat for relation head
    k_cat<<<Nn, 256, 0, stream>>>(noutb, newcib, hts,      cat1);
    k_cat<<<Nn, 256, 0, stream>>>(noutb, newcib, hts + Pp, cat2);
    // 17. nh / nt
    gemm(cat1, Wh, bh, act1, Nn, Dm, 2 * Dm, 1, 1, 0, 0, 0);
    gemm(cat2, Wt, bt, act2, Nn, Dm, 2 * Dm, 1, 1, 0, 0, 0);
    // 18. relation bilinear -> out1
    k_gbl<Rr><<<dim3((Nn + 127) / 128, Hh), 256, 0, stream>>>(act1, act2, Wrel, partb);
    k_gbl_reduce<<<(Nn * Rr + 255) / 256, 256, 0, stream>>>(partb, brel, out1, Rr, Nn * Rr);

    (void)in_sizes; (void)n_in; (void)out_size; (void)ws_size;
}

// Round 4
// 1056.298 us; speedup vs baseline: 2.7708x; 2.7708x over previous
//
#include <hip/hip_runtime.h>
#include <hip/hip_bf16.h>

// ---------------- problem constants ----------------
#define Bn   4
#define Lq   1024
#define Dm   768
#define Mm   48
#define NEe  24
#define Pp   552          // NE*(NE-1)
#define Ee   576          // P + NE (self loops)
#define Hh   12
#define BSz  64
#define Rr   97
#define Nn   2208         // B*P
#define NPAD 112          // Rr padded to 7*16
#define NEG_SLOPE 0.2f

typedef short bf16x8 __attribute__((ext_vector_type(8)));
typedef float f32x4  __attribute__((ext_vector_type(4)));

static __device__ __forceinline__ ushort f2b(float x) {
    __hip_bfloat16 h = __float2bfloat16(x);
    return *reinterpret_cast<ushort*>(&h);
}

// ============================================================
// entity[b,n,d] = log( sum_m emap[b,n,m] * exp(ctx[b, mmap[b,m], d]) )
__global__ void k_entity(const float* __restrict__ ctx, const int* __restrict__ mmap,
                         const float* __restrict__ emap, float* __restrict__ entity)
{
    int x = blockIdx.x;              // b*NE + n
    int b = x / NEe;
    int rows[8]; float wts[8]; int nnz = 0;
    for (int m = 0; m < Mm; ++m) {
        float w = emap[(long)x * Mm + m];
        if (w != 0.f && nnz < 8) { rows[nnz] = mmap[b * Mm + m]; wts[nnz] = w; ++nnz; }
    }
    const float* cbase = ctx + (long)b * Lq * Dm;
    for (int d = threadIdx.x; d < Dm; d += 256) {
        float s = 0.f;
        for (int z = 0; z < nnz; ++z) s += wts[z] * expf(cbase[(long)rows[z] * Dm + d]);
        entity[(long)x * Dm + d] = logf(s);
    }
}

__global__ void k_cur(const float* __restrict__ att, const int* __restrict__ mmap,
                      const float* __restrict__ emap, float* __restrict__ cur)
{
    int x = blockIdx.x;
    int b = x / (Hh * NEe); int rem = x % (Hh * NEe);
    int h = rem / NEe;      int n = rem % NEe;
    float cnt = 0.f;
    int rows[8]; float wts[8]; int nnz = 0;
    for (int m = 0; m < Mm; ++m) {
        float w = emap[((long)b * NEe + n) * Mm + m];
        cnt += w;
        if (w != 0.f && nnz < 8) { rows[nnz] = mmap[b * Mm + m]; wts[nnz] = w; ++nnz; }
    }
    float inv = 1.f / (cnt + 1e-20f);
    const float* abase = att + ((long)b * Hh + h) * (long)Lq * Lq;
    float* obase = cur + (long)x * Lq;
    for (int l = threadIdx.x; l < Lq; l += 256) {
        float s = 0.f;
        for (int z = 0; z < nnz; ++z) s += wts[z] * abase[(long)rows[z] * Lq + l];
        obase[l] = s * inv;
    }
}

__global__ void k_ca(const float* __restrict__ cur, const int* __restrict__ hts,
                     float* __restrict__ ca)
{
    int bp = blockIdx.x; int b = bp / Pp, p = bp % Pp;
    int n0 = hts[p], n1 = hts[Pp + p];
    __shared__ float red[256];
    float vals[4]; float lsum = 0.f;
    for (int t = 0; t < 4; ++t) {
        int l = threadIdx.x + t * 256;
        float v = 0.f;
        #pragma unroll
        for (int h = 0; h < Hh; ++h) {
            v += cur[(((long)b * Hh + h) * NEe + n0) * Lq + l] *
                 cur[(((long)b * Hh + h) * NEe + n1) * Lq + l];
        }
        vals[t] = v; lsum += v;
    }
    red[threadIdx.x] = lsum; __syncthreads();
    for (int s = 128; s > 0; s >>= 1) {
        if (threadIdx.x < s) red[threadIdx.x] += red[threadIdx.x + s];
        __syncthreads();
    }
    float inv = 1.f / (red[0] + 1e-20f);
    for (int t = 0; t < 4; ++t) {
        int l = threadIdx.x + t * 256;
        ca[(long)bp * Lq + l] = vals[t] * inv;
    }
}

// generic tiled f32 GEMM (ci path), C = A[M,K] @ W[K,N], batched
__global__ __launch_bounds__(256)
void k_gemm(const float* __restrict__ A, const float* __restrict__ W,
            float* __restrict__ C, int M, int N, int K, long sA, long sW, long sC)
{
    A += (long)blockIdx.z * sA;
    W += (long)blockIdx.z * sW;
    C += (long)blockIdx.z * sC;
    __shared__ float As[16][68];
    __shared__ float Ws[16][68];
    const int tid = threadIdx.x;
    const int tx = tid & 15, ty = tid >> 4;
    const int row0 = blockIdx.y * 64, col0 = blockIdx.x * 64;
    float acc[4][4] = {};
    for (int k0 = 0; k0 < K; k0 += 16) {
        #pragma unroll
        for (int s = 0; s < 4; ++s) {
            int idx = tid + s * 256;
            int r = idx >> 4, kk = idx & 15;
            int gr = row0 + r;
            As[kk][r] = (gr < M) ? A[(long)gr * K + k0 + kk] : 0.f;
        }
        #pragma unroll
        for (int s = 0; s < 4; ++s) {
            int idx = tid + s * 256;
            int kk = idx >> 6, cc = idx & 63;
            Ws[kk][cc] = W[(long)(k0 + kk) * N + col0 + cc];
        }
        __syncthreads();
        #pragma unroll
        for (int kk = 0; kk < 16; ++kk) {
            float w0 = Ws[kk][tx * 4 + 0], w1 = Ws[kk][tx * 4 + 1];
            float w2 = Ws[kk][tx * 4 + 2], w3 = Ws[kk][tx * 4 + 3];
            #pragma unroll
            for (int i2 = 0; i2 < 4; ++i2) {
                float av = As[kk][ty * 4 + i2];
                acc[i2][0] += av * w0; acc[i2][1] += av * w1;
                acc[i2][2] += av * w2; acc[i2][3] += av * w3;
            }
        }
        __syncthreads();
    }
    #pragma unroll
    for (int i2 = 0; i2 < 4; ++i2) {
        int gr = row0 + ty * 4 + i2;
        if (gr >= M) continue;
        #pragma unroll
        for (int j2 = 0; j2 < 4; ++j2) {
            int gc = col0 + tx * 4 + j2;
            C[(long)gr * N + gc] = acc[i2][j2];
        }
    }
}

// f32 GEMM with virtual concat A = [ent[sel[p]] | ci[g]]  (bin path, tanh)
__global__ __launch_bounds__(256)
void k_gemm_cat(const float* __restrict__ ent, const float* __restrict__ ci,
                const int* __restrict__ sel, const float* __restrict__ W,
                const float* __restrict__ bias, float* __restrict__ C)
{
    __shared__ float As[16][68];
    __shared__ float Ws[16][68];
    const int tid = threadIdx.x;
    const int tx = tid & 15, ty = tid >> 4;
    const int row0 = blockIdx.y * 64, col0 = blockIdx.x * 64;
    const float* eRow[4]; const float* cRow[4];
    #pragma unroll
    for (int s = 0; s < 4; ++s) {
        int gr = row0 + (tid >> 4) + s * 16;
        if (gr >= Nn) gr = Nn - 1;            // finite dup row; stores are guarded
        int b = gr / Pp, p = gr % Pp;
        eRow[s] = ent + ((long)b * NEe + sel[p]) * Dm;
        cRow[s] = ci + (long)gr * Dm;
    }
    float acc[4][4] = {};
    for (int k0 = 0; k0 < 2 * Dm; k0 += 16) {
        #pragma unroll
        for (int s = 0; s < 4; ++s) {
            int r = (tid >> 4) + s * 16;
            int k = k0 + tx;
            As[tx][r] = (k < Dm) ? eRow[s][k] : cRow[s][k - Dm];
        }
        #pragma unroll
        for (int s = 0; s < 4; ++s) {
            int idx = tid + s * 256;
            int kk = idx >> 6, cc = idx & 63;
            Ws[kk][cc] = W[(long)(k0 + kk) * Dm + col0 + cc];
        }
        __syncthreads();
        #pragma unroll
        for (int kk = 0; kk < 16; ++kk) {
            float w0 = Ws[kk][tx * 4 + 0], w1 = Ws[kk][tx * 4 + 1];
            float w2 = Ws[kk][tx * 4 + 2], w3 = Ws[kk][tx * 4 + 3];
            #pragma unroll
            for (int i2 = 0; i2 < 4; ++i2) {
                float av = As[kk][ty * 4 + i2];
                acc[i2][0] += av * w0; acc[i2][1] += av * w1;
                acc[i2][2] += av * w2; acc[i2][3] += av * w3;
            }
        }
        __syncthreads();
    }
    #pragma unroll
    for (int i2 = 0; i2 < 4; ++i2) {
        int gr = row0 + ty * 4 + i2;
        if (gr >= Nn) continue;
        #pragma unroll
        for (int j2 = 0; j2 < 4; ++j2) {
            int gc = col0 + tx * 4 + j2;
            C[(long)gr * Dm + gc] = tanhf(acc[i2][j2] + bias[gc]);
        }
    }
}

// ---------- weight transpose + bf16 convert: out[N][K] <- in[K][N] ----------
__global__ void k_wT(const float* __restrict__ in, ushort* __restrict__ out, int K, int N)
{
    __shared__ float t[32][33];
    int k0 = blockIdx.y * 32, n0 = blockIdx.x * 32;
    int tx = threadIdx.x & 31, ty = threadIdx.x >> 5;   // 256 thr: ty 0..7
    #pragma unroll
    for (int s = 0; s < 4; ++s)
        t[ty + s * 8][tx] = in[(long)(k0 + ty + s * 8) * N + n0 + tx];
    __syncthreads();
    #pragma unroll
    for (int s = 0; s < 4; ++s)
        out[(long)(n0 + ty + s * 8) * K + k0 + tx] = f2b(t[tx][ty + s * 8]);
}

// Wrel [(h*64+i)*64+j][97] -> WrelB[(hi*112 + o)*64 + j] bf16 (o>=97 -> 0)
__global__ void k_wrelT(const float* __restrict__ W, ushort* __restrict__ out)
{
    int hi = blockIdx.x;            // 0..767
    for (int idx = threadIdx.x; idx < NPAD * 64; idx += 256) {
        int o = idx >> 6, j = idx & 63;
        float v = (o < Rr) ? W[((long)hi * 64 + j) * Rr + o] : 0.f;
        out[(long)hi * NPAD * 64 + idx] = f2b(v);
    }
}

// f32 -> bf16 flat convert (n4 = n/4)
__global__ void k_f2bf(const float* __restrict__ in, ushort* __restrict__ out, int n4)
{
    int i = blockIdx.x * 256 + threadIdx.x;
    if (i >= n4) return;
    float4 v = ((const float4*)in)[i];
    ushort4 o;
    o.x = f2b(v.x); o.y = f2b(v.y); o.z = f2b(v.z); o.w = f2b(v.w);
    ((ushort4*)out)[i] = o;
}

// ---------- bf16 MFMA GEMM: C[M][ldc] = A[M][K] @ Bt[N][K]^T ----------
// grid (N/128, ceil(M/128)), 256 thr = 4 waves, each wave 64x64
// staging: 2 threads/row, each loads 2x uint4 => full 32-ushort K-tile per row
__global__ __launch_bounds__(256)
void k_gemm_bf(const ushort* __restrict__ A, const ushort* __restrict__ Bt,
               float* __restrict__ C, int M, int N, int K, int ldc)
{
    __shared__ ushort As[128][40];
    __shared__ ushort Bs[128][40];
    const int tid = threadIdx.x;
    const int r0 = blockIdx.y * 128, c0 = blockIdx.x * 128;
    const int w = tid >> 6, l = tid & 63, lr = l & 15, lk = l >> 4;
    const int wr = (w >> 1) * 64, wc = (w & 1) * 64;
    f32x4 acc[4][4];
    #pragma unroll
    for (int m = 0; m < 4; ++m)
        #pragma unroll
        for (int n = 0; n < 4; ++n) acc[m][n] = (f32x4){0.f, 0.f, 0.f, 0.f};

    const int srow = tid >> 1, scb = (tid & 1) * 16;
    const uint4 z4 = make_uint4(0, 0, 0, 0);
    for (int k0 = 0; k0 < K; k0 += 32) {
        long gr = r0 + srow, gc = c0 + srow;
        const bool aok = gr < M, bok = gc < N;
        const ushort* ap = &A[gr * (long)K + k0 + scb];
        const ushort* bp = &Bt[gc * (long)K + k0 + scb];
        *(uint4*)&As[srow][scb]     = aok ? *(const uint4*)ap       : z4;
        *(uint4*)&As[srow][scb + 8] = aok ? *(const uint4*)(ap + 8) : z4;
        *(uint4*)&Bs[srow][scb]     = bok ? *(const uint4*)bp       : z4;
        *(uint4*)&Bs[srow][scb + 8] = bok ? *(const uint4*)(bp + 8) : z4;
        __syncthreads();
        bf16x8 af[4], bfr[4];
        #pragma unroll
        for (int m = 0; m < 4; ++m) af[m]  = *(const bf16x8*)&As[wr + m * 16 + lr][lk * 8];
        #pragma unroll
        for (int n = 0; n < 4; ++n) bfr[n] = *(const bf16x8*)&Bs[wc + n * 16 + lr][lk * 8];
        #pragma unroll
        for (int m = 0; m < 4; ++m)
            #pragma unroll
            for (int n = 0; n < 4; ++n)
                acc[m][n] = __builtin_amdgcn_mfma_f32_16x16x32_bf16(af[m], bfr[n], acc[m][n], 0, 0, 0);
        __syncthreads();
    }
    #pragma unroll
    for (int m = 0; m < 4; ++m) {
        #pragma unroll
        for (int q = 0; q < 4; ++q) {
            int gr = r0 + wr + m * 16 + lk * 4 + q;
            if (gr >= M) continue;
            #pragma unroll
            for (int n = 0; n < 4; ++n) {
                int gc = c0 + wc + n * 16 + lr;
                C[(long)gr * ldc + gc] = acc[m][n][q];
            }
        }
    }
}

// bf16 MFMA GEMM with virtual concat A = [nodes[sel[p]] | feat[g]], tanh epilogue
// M=Nn, K=2*Dm, N=Dm, ldc=Dm. grid (Dm/128, ceil(Nn/128))
__global__ __launch_bounds__(256)
void k_gemm_bf_cat(const ushort* __restrict__ nodes, const ushort* __restrict__ feat,
                   const int* __restrict__ sel, const ushort* __restrict__ Bt,
                   const float* __restrict__ bias, float* __restrict__ C)
{
    __shared__ ushort As[128][40];
    __shared__ ushort Bs[128][40];
    const int tid = threadIdx.x;
    const int r0 = blockIdx.y * 128, c0 = blockIdx.x * 128;
    const int w = tid >> 6, l = tid & 63, lr = l & 15, lk = l >> 4;
    const int wr = (w >> 1) * 64, wc = (w & 1) * 64;
    f32x4 acc[4][4];
    #pragma unroll
    for (int m = 0; m < 4; ++m)
        #pragma unroll
        for (int n = 0; n < 4; ++n) acc[m][n] = (f32x4){0.f, 0.f, 0.f, 0.f};

    const int srow = tid >> 1, scb = (tid & 1) * 16;
    const int gra = r0 + srow;
    const bool a_ok = gra < Nn;
    const int grc = a_ok ? gra : Nn - 1;
    const int b = grc / Pp, p = grc % Pp;
    const ushort* pe = nodes + ((long)b * NEe + sel[p]) * Dm;
    const ushort* pc = feat + (long)grc * Dm;
    const int gc = c0 + srow;        // N=768, always < N
    const uint4 z4 = make_uint4(0, 0, 0, 0);
    for (int k0 = 0; k0 < 2 * Dm; k0 += 32) {
        const ushort* src = (k0 < Dm) ? (pe + k0 + scb) : (pc + (k0 - Dm) + scb);
        const ushort* bp  = &Bt[(long)gc * (2 * Dm) + k0 + scb];
        *(uint4*)&As[srow][scb]     = a_ok ? *(const uint4*)src       : z4;
        *(uint4*)&As[srow][scb + 8] = a_ok ? *(const uint4*)(src + 8) : z4;
        *(uint4*)&Bs[srow][scb]     = *(const uint4*)bp;
        *(uint4*)&Bs[srow][scb + 8] = *(const uint4*)(bp + 8);
        __syncthreads();
        bf16x8 af[4], bfr[4];
        #pragma unroll
        for (int m = 0; m < 4; ++m) af[m]  = *(const bf16x8*)&As[wr + m * 16 + lr][lk * 8];
        #pragma unroll
        for (int n = 0; n < 4; ++n) bfr[n] = *(const bf16x8*)&Bs[wc + n * 16 + lr][lk * 8];
        #pragma unroll
        for (int m = 0; m < 4; ++m)
            #pragma unroll
            for (int n = 0; n < 4; ++n)
                acc[m][n] = __builtin_amdgcn_mfma_f32_16x16x32_bf16(af[m], bfr[n], acc[m][n], 0, 0, 0);
        __syncthreads();
    }
    #pragma unroll
    for (int m = 0; m < 4; ++m) {
        #pragma unroll
        for (int q = 0; q < 4; ++q) {
            int gr = r0 + wr + m * 16 + lk * 4 + q;
            if (gr >= Nn) continue;
            #pragma unroll
            for (int n = 0; n < 4; ++n) {
                int gcc = c0 + wc + n * 16 + lr;
                C[(long)gr * Dm + gcc] = tanhf(acc[m][n][q] + bias[gcc]);
            }
        }
    }
}

// ---------- MFMA blockwise bilinear (relation head) ----------
// part[h][n][o<112] = sum_{i,j} a[n,h,i]*c[n,h,j]*W[h,i,j,o]
// grid (ceil(Nn/128), 12 h), 256 thr = 4 waves x 32 rows
__global__ __launch_bounds__(256)
void k_gbl_mfma(const float* __restrict__ Aact, const float* __restrict__ Cact,
                const ushort* __restrict__ Wt, float* __restrict__ part)
{
    const int h = blockIdx.y;
    const int r0 = blockIdx.x * 128;
    __shared__ float a_s[128][68];
    const int tid = threadIdx.x;
    {   // stage a-block [128][64]
        int row = tid >> 1, cb = (tid & 1) * 32;
        long gr = r0 + row;
        if (gr < Nn) {
            const float* ap = Aact + gr * Dm + h * BSz + cb;
            #pragma unroll
            for (int q = 0; q < 32; q += 4)
                *(float4*)&a_s[row][cb + q] = *(const float4*)&ap[q];
        } else {
            #pragma unroll
            for (int q = 0; q < 32; ++q) a_s[row][cb + q] = 0.f;
        }
    }
    __syncthreads();
    const int w = tid >> 6, l = tid & 63, lr = l & 15, lk = l >> 4;
    const int wr = w * 32;
    f32x4 acc[2][7];
    #pragma unroll
    for (int m = 0; m < 2; ++m)
        #pragma unroll
        for (int n = 0; n < 7; ++n) acc[m][n] = (f32x4){0.f, 0.f, 0.f, 0.f};

    const ushort* wbase = Wt + (long)h * 64 * NPAD * 64;   // [i][o][j]
    for (int j0 = 0; j0 < 64; j0 += 32) {
        float cc[2][8];
        #pragma unroll
        for (int m = 0; m < 2; ++m) {
            int crow = r0 + wr + m * 16 + lr;
            if (crow >= Nn) crow = Nn - 1;   // a=0 there anyway
            const float* cp = Cact + (long)crow * Dm + h * BSz + j0 + lk * 8;
            float4 clo = *(const float4*)cp;
            float4 chi = *(const float4*)(cp + 4);
            cc[m][0] = clo.x; cc[m][1] = clo.y; cc[m][2] = clo.z; cc[m][3] = clo.w;
            cc[m][4] = chi.x; cc[m][5] = chi.y; cc[m][6] = chi.z; cc[m][7] = chi.w;
        }
        for (int i = 0; i < 64; ++i) {
            bf16x8 bfr[7];
            const ushort* wp = wbase + (long)i * NPAD * 64 + j0 + lk * 8;
            #pragma unroll
            for (int n = 0; n < 7; ++n)
                bfr[n] = *(const bf16x8*)(wp + (long)(n * 16 + lr) * 64);
            #pragma unroll
            for (int m = 0; m < 2; ++m) {
                float av = a_s[wr + m * 16 + lr][i];
                bf16x8 af;
                #pragma unroll
                for (int q = 0; q < 8; ++q)
                    af[q] = (short)f2b(av * cc[m][q]);
                #pragma unroll
                for (int n = 0; n < 7; ++n)
                    acc[m][n] = __builtin_amdgcn_mfma_f32_16x16x32_bf16(af, bfr[n], acc[m][n], 0, 0, 0);
            }
        }
    }
    #pragma unroll
    for (int m = 0; m < 2; ++m) {
        #pragma unroll
        for (int q = 0; q < 4; ++q) {
            int gr = r0 + wr + m * 16 + lk * 4 + q;
            if (gr >= Nn) continue;
            #pragma unroll
            for (int n = 0; n < 7; ++n) {
                int o = n * 16 + lr;
                part[((long)h * Nn + gr) * NPAD + o] = acc[m][n][q];
            }
        }
    }
}

__global__ void k_rel_reduce(const float* __restrict__ part, const float* __restrict__ bias,
                             float* __restrict__ out)
{
    int idx = blockIdx.x * 256 + threadIdx.x;
    if (idx >= Nn * Rr) return;
    int n = idx / Rr, o = idx % Rr;
    float s = bias[o];
    #pragma unroll
    for (int h = 0; h < Hh; ++h) s += part[((long)h * Nn + n) * NPAD + o];
    out[idx] = s;
}

// ---------- f32 bilinear for bin head (precision-critical) ----------
template<int RR>
__global__ __launch_bounds__(256)
void k_gbl(const float* __restrict__ Aact, const float* __restrict__ Cact,
           const float* __restrict__ W, float* __restrict__ part)
{
    __shared__ float a_s[128][65];
    __shared__ float c_s[128][65];
    const int h = blockIdx.y;
    const int row0 = blockIdx.x * 128;
    const int tid = threadIdx.x;
    const int rg = tid >> 3;
    const int c  = tid & 7;
    const int r0l = rg * 4;
    #pragma unroll
    for (int s = 0; s < 32; ++s) {
        int idx = tid + s * 256;
        int r = idx >> 6, col = idx & 63;
        int gr = row0 + r;
        float av = 0.f, cv = 0.f;
        if (gr < Nn) {
            av = Aact[(long)gr * Dm + h * BSz + col];
            cv = Cact[(long)gr * Dm + h * BSz + col];
        }
        a_s[r][col] = av;
        c_s[r][col] = cv;
    }
    __syncthreads();
    constexpr int NC = (RR + 7) / 8;
    float acc[4][NC];
    #pragma unroll
    for (int k = 0; k < 4; ++k)
        #pragma unroll
        for (int m = 0; m < NC; ++m) acc[k][m] = 0.f;

    for (int i = 0; i < BSz; ++i) {
        float av0 = a_s[r0l + 0][i], av1 = a_s[r0l + 1][i];
        float av2 = a_s[r0l + 2][i], av3 = a_s[r0l + 3][i];
        const float* wrow = W + ((long)(h * BSz + i) * BSz) * RR;
        for (int j = 0; j < BSz; ++j) {
            float cv0 = c_s[r0l + 0][j], cv1 = c_s[r0l + 1][j];
            float cv2 = c_s[r0l + 2][j], cv3 = c_s[r0l + 3][j];
            float f0 = av0 * cv0, f1 = av1 * cv1, f2 = av2 * cv2, f3 = av3 * cv3;
            const float* wj = wrow + (long)j * RR;
            #pragma unroll
            for (int m = 0; m < NC; ++m) {
                int o = c + 8 * m;
                if (o < RR) {
                    float wv = wj[o];
                    acc[0][m] += f0 * wv; acc[1][m] += f1 * wv;
                    acc[2][m] += f2 * wv; acc[3][m] += f3 * wv;
                }
            }
        }
    }
    #pragma unroll
    for (int k = 0; k < 4; ++k) {
        int gr = row0 + r0l + k;
        if (gr < Nn) {
            #pragma unroll
            for (int m = 0; m < NC; ++m) {
                int o = c + 8 * m;
                if (o < RR) part[((long)h * Nn + gr) * RR + o] = acc[k][m];
            }
        }
    }
}

__global__ void k_gbl_reduce(const float* __restrict__ part, const float* __restrict__ bias,
                             float* __restrict__ out, int RR, int total)
{
    int idx = blockIdx.x * 256 + threadIdx.x;
    if (idx >= total) return;
    int o = idx % RR;
    float s = bias[o];
    for (int h = 0; h < Hh; ++h) s += part[(long)h * Nn * RR + idx];
    out[idx] = s;
}

__global__ void k_mask(const float* __restrict__ bin, int* __restrict__ mask)
{
    int idx = blockIdx.x * 256 + threadIdx.x;
    if (idx >= Nn) return;
    mask[idx] = bin[idx * 2 + 1] > bin[idx * 2 + 0] ? 1 : 0;
}

// f_out[b,e,:] = (e<P ? fij[b,e] : 0) + ni[b,src] + nj[b,dst] + egat_b
__global__ void k_fassemble(const float* __restrict__ fij, const float* __restrict__ ni,
                            const float* __restrict__ nj, const float* __restrict__ eb,
                            const int* __restrict__ hts, float* __restrict__ fout, int ldn)
{
    int be = blockIdx.x; int b = be / Ee, e = be % Ee;
    int sn, dn; const float* fe = nullptr;
    if (e < Pp) { sn = hts[e]; dn = hts[Pp + e]; fe = fij + ((long)b * Pp + e) * Dm; }
    else        { sn = dn = e - Pp; }
    const float* nib = ni + ((long)b * NEe + sn) * ldn;
    const float* njb = nj + ((long)b * NEe + dn) * ldn;
    float* ob = fout + (long)be * Dm;
    for (int d = threadIdx.x; d < Dm; d += 256)
        ob[d] = (fe ? fe[d] : 0.f) + nib[d] + njb[d] + eb[d];
}

__global__ void k_score(const float* __restrict__ fout, const float* __restrict__ attp,
                        const int* __restrict__ mask, float* __restrict__ score)
{
    int idx = blockIdx.x * 256 + threadIdx.x;
    if (idx >= Bn * Ee * Hh) return;
    int h = idx % Hh; int be = idx / Hh; int b = be / Ee, e = be % Ee;
    const float* fb = fout + (long)be * Dm + h * BSz;
    const float* ap = attp + h * BSz;
    float s = 0.f;
    for (int j = 0; j < BSz; ++j) {
        float v = fb[j];
        float lr = v >= 0.f ? v : NEG_SLOPE * v;
        s += lr * ap[j];
    }
    bool ok = (e >= Pp) || (mask[b * Pp + e] != 0);
    score[idx] = ok ? s : -1e30f;
}

__global__ void k_segsoft(const float* __restrict__ score, float* __restrict__ attw)
{
    int idx = blockIdx.x * 256 + threadIdx.x;
    if (idx >= Bn * NEe * Hh) return;
    int h = idx % Hh; int bnn = idx / Hh; int b = bnn / NEe, n = bnn % NEe;
    float sc[NEe]; int es[NEe];
    float smax = -3e38f;
    #pragma unroll
    for (int hh = 0; hh < NEe; ++hh) {
        int e;
        if (hh == n) e = Pp + n;
        else         e = hh * (NEe - 1) + (n - (n > hh ? 1 : 0));
        float v = score[((long)b * Ee + e) * Hh + h];
        es[hh] = e; sc[hh] = v;
        smax = fmaxf(smax, v);
    }
    float den = 0.f;
    #pragma unroll
    for (int z = 0; z < NEe; ++z) { sc[z] = expf(sc[z] - smax); den += sc[z]; }
    float inv = 1.f / (den + 1e-20f);
    #pragma unroll
    for (int z = 0; z < NEe; ++z)
        attw[((long)b * Ee + es[z]) * Hh + h] = sc[z] * inv;
}

// node aggregation -> bf16 output (only consumer is the relation GEMM)
__global__ void k_nodeout_bf(const float* __restrict__ hsrcB, const float* __restrict__ attw,
                             ushort* __restrict__ nout, int ldn)
{
    int bnn = blockIdx.x; int b = bnn / NEe, n = bnn % NEe;
    for (int d = threadIdx.x; d < Dm; d += 256) {
        int h = d >> 6;
        float s = 0.f;
        #pragma unroll
        for (int hh = 0; hh < NEe; ++hh) {
            int e, sn;
            if (hh == n) { e = Pp + n; sn = n; }
            else         { e = hh * (NEe - 1) + (n - (n > hh ? 1 : 0)); sn = hh; }
            s += hsrcB[((long)b * NEe + sn) * ldn + d] * attw[((long)b * Ee + e) * Hh + h];
        }
        nout[(long)bnn * Dm + d] = f2b(s);
    }
}

// new_ci = mask ? f_out[:P] : ci  -> bf16 (only consumer is the relation GEMM)
__global__ void k_newci_bf(const float* __restrict__ fout, const float* __restrict__ ci,
                           const int* __restrict__ mask, ushort* __restrict__ out)
{
    int idx = blockIdx.x * 256 + threadIdx.x;
    if (idx >= Nn * Dm) return;
    int n = idx / Dm, d = idx % Dm;
    int b = n / Pp, p = n % Pp;
    out[idx] = f2b(mask[n] ? fout[((long)b * Ee + p) * Dm + d] : ci[idx]);
}

// ============================================================
extern "C" void kernel_launch(void* const* d_in, const int* in_sizes, int n_in,
                              void* d_out, int out_size, void* d_ws, size_t ws_size,
                              hipStream_t stream)
{
    const float* ctx   = (const float*)d_in[0];
    const float* att   = (const float*)d_in[1];
    const int*   mmap  = (const int*)d_in[2];
    const float* emap  = (const float*)d_in[3];
    const int*   hts   = (const int*)d_in[4];
    const float* Whb   = (const float*)d_in[5];
    const float* bhb   = (const float*)d_in[6];
    const float* Wtb   = (const float*)d_in[7];
    const float* btb   = (const float*)d_in[8];
    const float* Wbin  = (const float*)d_in[9];
    const float* bbin  = (const float*)d_in[10];
    const float* Wrel  = (const float*)d_in[11];
    const float* brel  = (const float*)d_in[12];
    const float* Wh    = (const float*)d_in[13];
    const float* bh    = (const float*)d_in[14];
    const float* Wt    = (const float*)d_in[15];
    const float* bt    = (const float*)d_in[16];
    const float* Wnode = (const float*)d_in[17];
    const float* Wni   = (const float*)d_in[18];
    const float* Wfij  = (const float*)d_in[19];
    const float* Wnj   = (const float*)d_in[20];
    const float* attp  = (const float*)d_in[21];
    const float* egatb = (const float*)d_in[22];

    float* out0 = (float*)d_out;            // bin_res [2208,2]
    float* out1 = out0 + (long)Nn * 2;      // relation_res [2208,97]

    // ---- workspace layout (float slots); total ~18.4M floats = 73.4 MB ----
    float* w = (float*)d_ws;
    size_t off = 0;
    auto alloc = [&](size_t nf) { float* p = w + off; off += nf; return p; };
    float* entity = alloc((size_t)Bn * NEe * Dm);          //    73,728
    float* curb   = alloc((size_t)Bn * Hh * NEe * Lq);     // 1,179,648  [partb alias]
    float* cab    = alloc((size_t)Bn * Pp * Lq);           // 2,260,992  [partb alias]
    float* cib    = alloc((size_t)Nn * Dm);                // 1,695,744
    float* act1   = alloc((size_t)Nn * Dm);                // 1,695,744
    float* act2   = alloc((size_t)Nn * Dm);                // 1,695,744
    float* fijb   = alloc((size_t)Nn * Dm);                // 1,695,744
    float* foutb  = alloc((size_t)Bn * Ee * Dm);           // 1,769,472
    float* comb   = alloc((size_t)Bn * NEe * 3 * Dm);      //   221,184  ni|nj|hsrc
    float* scoreb = alloc((size_t)Bn * Ee * Hh);           //    27,648
    float* attwb  = alloc((size_t)Bn * Ee * Hh);           //    27,648
    int*   maskb  = (int*)alloc(Nn);                       //     2,208
    ushort* entbf = (ushort*)alloc((size_t)Bn * NEe * Dm / 2);  // 36,864  [noutbf alias]
    ushort* cibbf = (ushort*)alloc((size_t)Nn * Dm / 2);        // 847,872 [newcibf alias]
    ushort* WTe   = (ushort*)alloc((size_t)3 * Dm * Dm / 2);    // 884,736  [2304][768]
    ushort* WfijT = (ushort*)alloc((size_t)Dm * Dm / 2);        // 294,912
    ushort* WhT   = (ushort*)alloc((size_t)Dm * 2 * Dm / 2);    // 589,824  [768][1536]
    ushort* WtT   = (ushort*)alloc((size_t)Dm * 2 * Dm / 2);    // 589,824
    ushort* WrelB = (ushort*)alloc((size_t)Dm * NPAD * 64 / 2); // 2,752,512 [768][112][64]
    // aliases (lifetimes disjoint):
    float*  partb   = curb;            // needs 12*2208*112 = 2,967,552 <= curb+cab
    ushort* noutbf  = entbf;           // entity-bf dead after comb gemm
    ushort* newcibf = cibbf;           // cib-bf dead after fij gemm

    // 0. weight conversions (input-only deps)
    k_wT<<<dim3(24, 24), 256, 0, stream>>>(Wni,   WTe,                 Dm, Dm);
    k_wT<<<dim3(24, 24), 256, 0, stream>>>(Wnj,   WTe + Dm * Dm,       Dm, Dm);
    k_wT<<<dim3(24, 24), 256, 0, stream>>>(Wnode, WTe + 2 * Dm * Dm,   Dm, Dm);
    k_wT<<<dim3(24, 24), 256, 0, stream>>>(Wfij,  WfijT,               Dm, Dm);
    k_wT<<<dim3(24, 48), 256, 0, stream>>>(Wh,    WhT,             2 * Dm, Dm);
    k_wT<<<dim3(24, 48), 256, 0, stream>>>(Wt,    WtT,             2 * Dm, Dm);
    k_wrelT<<<Dm, 256, 0, stream>>>(Wrel, WrelB);

    // 1-4. pooling + ci (f32, precision-critical for mask)
    k_entity<<<Bn * NEe, 256, 0, stream>>>(ctx, mmap, emap, entity);
    k_cur<<<Bn * Hh * NEe, 256, 0, stream>>>(att, mmap, emap, curb);
    k_ca<<<Bn * Pp, 256, 0, stream>>>(curb, hts, cab);
    k_gemm<<<dim3(Dm / 64, (Pp + 63) / 64, Bn), 256, 0, stream>>>(
        cab, ctx, cib, Pp, Dm, Lq, (long)Pp * Lq, (long)Lq * Dm, (long)Pp * Dm);

    // 5-8. bin head (f32, gathered concat) + mask
    k_gemm_cat<<<dim3(Dm / 64, (Nn + 63) / 64), 256, 0, stream>>>(entity, cib, hts,      Whb, bhb, act1);
    k_gemm_cat<<<dim3(Dm / 64, (Nn + 63) / 64), 256, 0, stream>>>(entity, cib, hts + Pp, Wtb, btb, act2);
    k_gbl<2><<<dim3((Nn + 127) / 128, Hh), 256, 0, stream>>>(act1, act2, Wbin, partb);
    k_gbl_reduce<<<(Nn * 2 + 255) / 256, 256, 0, stream>>>(partb, bbin, out0, 2, Nn * 2);
    k_mask<<<(Nn + 255) / 256, 256, 0, stream>>>(out0, maskb);

    // 9-10. EGAT linears (fused, bf16 MFMA) + fij
    k_f2bf<<<(Bn * NEe * Dm / 4 + 255) / 256, 256, 0, stream>>>(entity, entbf, Bn * NEe * Dm / 4);
    k_gemm_bf<<<dim3(3 * Dm / 128, 1), 256, 0, stream>>>(entbf, WTe, comb, Bn * NEe, 3 * Dm, Dm, 3 * Dm);
    k_f2bf<<<(Nn * Dm / 4 + 255) / 256, 256, 0, stream>>>(cib, cibbf, Nn * Dm / 4);
    k_gemm_bf<<<dim3(Dm / 128, (Nn + 127) / 128), 256, 0, stream>>>(cibbf, WfijT, fijb, Nn, Dm, Dm, Dm);

    // 11-15. EGAT attention + new_ci (bf16 outputs)
    k_fassemble<<<Bn * Ee, 256, 0, stream>>>(fijb, comb, comb + Dm, egatb, hts, foutb, 3 * Dm);
    k_score<<<(Bn * Ee * Hh + 255) / 256, 256, 0, stream>>>(foutb, attp, maskb, scoreb);
    k_segsoft<<<(Bn * NEe * Hh + 255) / 256, 256, 0, stream>>>(scoreb, attwb);
    k_nodeout_bf<<<Bn * NEe, 256, 0, stream>>>(comb + 2 * Dm, attwb, noutbf, 3 * Dm);
    k_newci_bf<<<(Nn * Dm + 255) / 256, 256, 0, stream>>>(foutb, cib, maskb, newcibf);

    // 16-17. relation head GEMMs (bf16 MFMA, gathered concat, tanh)
    k_gemm_bf_cat<<<dim3(Dm / 128, (Nn + 127) / 128), 256, 0, stream>>>(noutbf, newcibf, hts,      WhT, bh, act1);
    k_gemm_bf_cat<<<dim3(Dm / 128, (Nn + 127) / 128), 256, 0, stream>>>(noutbf, newcibf, hts + Pp, WtT, bt, act2);

    // 18. relation bilinear (MFMA) -> out1
    k_gbl_mfma<<<dim3((Nn + 127) / 128, Hh), 256, 0, stream>>>(act1, act2, WrelB, partb);
    k_rel_reduce<<<(Nn * Rr + 255) / 256, 256, 0, stream>>>(partb, brel, out1);

    (void)in_sizes; (void)n_in; (void)out_size; (void)ws_size;
}

// Round 5
// 669.028 us; speedup vs baseline: 4.3747x; 1.5789x over previous
//
#include <hip/hip_runtime.h>
#include <hip/hip_bf16.h>

// ---------------- problem constants ----------------
#define Bn   4
#define Lq   1024
#define Dm   768
#define Mm   48
#define NEe  24
#define Pp   552          // NE*(NE-1)
#define Ee   576          // P + NE (self loops)
#define Hh   12
#define BSz  64
#define Rr   97
#define Nn   2208         // B*P
#define NPAD 112          // Rr padded to 7*16
#define NEG_SLOPE 0.2f

typedef short bf16x8 __attribute__((ext_vector_type(8)));
typedef float f32x4  __attribute__((ext_vector_type(4)));

static __device__ __forceinline__ ushort f2b(float x) {
    __hip_bfloat16 h = __float2bfloat16(x);
    return *reinterpret_cast<ushort*>(&h);
}
static __device__ __forceinline__ float b2f(ushort h) {
    uint u = ((uint)h) << 16;
    return __uint_as_float(u);
}
// split f32 into hi+lo bf16 (a ~= hi + lo, residual ~2^-18 rel)
static __device__ __forceinline__ void split2(float x, ushort& h, ushort& l) {
    h = f2b(x);
    l = f2b(x - b2f(h));
}

// ============================================================
// entity[b,n,d] = log( sum_m emap[b,n,m] * exp(ctx[b, mmap[b,m], d]) )
__global__ void k_entity(const float* __restrict__ ctx, const int* __restrict__ mmap,
                         const float* __restrict__ emap, float* __restrict__ entity)
{
    int x = blockIdx.x;              // b*NE + n
    int b = x / NEe;
    int rows[8]; float wts[8]; int nnz = 0;
    for (int m = 0; m < Mm; ++m) {
        float w = emap[(long)x * Mm + m];
        if (w != 0.f && nnz < 8) { rows[nnz] = mmap[b * Mm + m]; wts[nnz] = w; ++nnz; }
    }
    const float* cbase = ctx + (long)b * Lq * Dm;
    for (int d = threadIdx.x; d < Dm; d += 256) {
        float s = 0.f;
        for (int z = 0; z < nnz; ++z) s += wts[z] * expf(cbase[(long)rows[z] * Dm + d]);
        entity[(long)x * Dm + d] = logf(s);
    }
}

__global__ void k_cur(const float* __restrict__ att, const int* __restrict__ mmap,
                      const float* __restrict__ emap, float* __restrict__ cur)
{
    int x = blockIdx.x;
    int b = x / (Hh * NEe); int rem = x % (Hh * NEe);
    int h = rem / NEe;      int n = rem % NEe;
    float cnt = 0.f;
    int rows[8]; float wts[8]; int nnz = 0;
    for (int m = 0; m < Mm; ++m) {
        float w = emap[((long)b * NEe + n) * Mm + m];
        cnt += w;
        if (w != 0.f && nnz < 8) { rows[nnz] = mmap[b * Mm + m]; wts[nnz] = w; ++nnz; }
    }
    float inv = 1.f / (cnt + 1e-20f);
    const float* abase = att + ((long)b * Hh + h) * (long)Lq * Lq;
    float* obase = cur + (long)x * Lq;
    for (int l = threadIdx.x; l < Lq; l += 256) {
        float s = 0.f;
        for (int z = 0; z < nnz; ++z) s += wts[z] * abase[(long)rows[z] * Lq + l];
        obase[l] = s * inv;
    }
}

__global__ void k_ca(const float* __restrict__ cur, const int* __restrict__ hts,
                     float* __restrict__ ca)
{
    int bp = blockIdx.x; int b = bp / Pp, p = bp % Pp;
    int n0 = hts[p], n1 = hts[Pp + p];
    __shared__ float red[256];
    float vals[4]; float lsum = 0.f;
    for (int t = 0; t < 4; ++t) {
        int l = threadIdx.x + t * 256;
        float v = 0.f;
        #pragma unroll
        for (int h = 0; h < Hh; ++h) {
            v += cur[(((long)b * Hh + h) * NEe + n0) * Lq + l] *
                 cur[(((long)b * Hh + h) * NEe + n1) * Lq + l];
        }
        vals[t] = v; lsum += v;
    }
    red[threadIdx.x] = lsum; __syncthreads();
    for (int s = 128; s > 0; s >>= 1) {
        if (threadIdx.x < s) red[threadIdx.x] += red[threadIdx.x + s];
        __syncthreads();
    }
    float inv = 1.f / (red[0] + 1e-20f);
    for (int t = 0; t < 4; ++t) {
        int l = threadIdx.x + t * 256;
        ca[(long)bp * Lq + l] = vals[t] * inv;
    }
}

// ============================================================
// split-bf16 (3-MFMA) GEMM, ~f32 accuracy: C = act(A[M,K] @ W[K,N] + bias)
// A f32 row-major (lda), W f32 row-major [K][N] (ldw), batched via z.
// BM=64, BN=64, BK=32; 256 thr = 4 waves of 32x32.
__global__ __launch_bounds__(256)
void k_gemm_split(const float* __restrict__ A, const float* __restrict__ W,
                  const float* __restrict__ bias, float* __restrict__ C,
                  int M, int N, int K, int lda, int ldw, int ldc,
                  long sA, long sW, long sC, int act)
{
    A += (long)blockIdx.z * sA;
    W += (long)blockIdx.z * sW;
    C += (long)blockIdx.z * sC;
    __shared__ ushort Ah[64][40], Al[64][40], Bh[64][40], Bl[64][40];
    const int tid = threadIdx.x;
    const int r0 = blockIdx.y * 64, c0 = blockIdx.x * 64;
    const int w = tid >> 6, l = tid & 63, lr = l & 15, lk = l >> 4;
    const int wr = (w >> 1) * 32, wc = (w & 1) * 32;
    f32x4 acc[2][2];
    #pragma unroll
    for (int m = 0; m < 2; ++m)
        #pragma unroll
        for (int n = 0; n < 2; ++n) acc[m][n] = (f32x4){0.f, 0.f, 0.f, 0.f};

    const int ar  = tid >> 3;            // staged A rows: ar, ar+32
    const int kq  = (tid & 7) * 4;
    const int bkk = tid >> 4;            // staged B k: bkk, bkk+16
    const int cc4 = (tid & 15) * 4;
    const float4 z4 = make_float4(0.f, 0.f, 0.f, 0.f);

    for (int k0 = 0; k0 < K; k0 += 32) {
        #pragma unroll
        for (int s = 0; s < 2; ++s) {
            int r = ar + s * 32;
            int gr = r0 + r;
            float4 v = (gr < M) ? *(const float4*)&A[(long)gr * lda + k0 + kq] : z4;
            ushort h0, l0, h1, l1;
            split2(v.x, h0, l0); split2(v.y, h1, l1);
            *(uint*)&Ah[r][kq]     = (uint)h0 | ((uint)h1 << 16);
            *(uint*)&Al[r][kq]     = (uint)l0 | ((uint)l1 << 16);
            split2(v.z, h0, l0); split2(v.w, h1, l1);
            *(uint*)&Ah[r][kq + 2] = (uint)h0 | ((uint)h1 << 16);
            *(uint*)&Al[r][kq + 2] = (uint)l0 | ((uint)l1 << 16);
        }
        #pragma unroll
        for (int s = 0; s < 2; ++s) {
            int kk = bkk + s * 16;
            float4 v = *(const float4*)&W[(long)(k0 + kk) * ldw + c0 + cc4];
            ushort hh, ll;
            split2(v.x, hh, ll); Bh[cc4 + 0][kk] = hh; Bl[cc4 + 0][kk] = ll;
            split2(v.y, hh, ll); Bh[cc4 + 1][kk] = hh; Bl[cc4 + 1][kk] = ll;
            split2(v.z, hh, ll); Bh[cc4 + 2][kk] = hh; Bl[cc4 + 2][kk] = ll;
            split2(v.w, hh, ll); Bh[cc4 + 3][kk] = hh; Bl[cc4 + 3][kk] = ll;
        }
        __syncthreads();
        bf16x8 fah[2], fal[2], fbh[2], fbl[2];
        #pragma unroll
        for (int m = 0; m < 2; ++m) {
            fah[m] = *(const bf16x8*)&Ah[wr + m * 16 + lr][lk * 8];
            fal[m] = *(const bf16x8*)&Al[wr + m * 16 + lr][lk * 8];
        }
        #pragma unroll
        for (int n = 0; n < 2; ++n) {
            fbh[n] = *(const bf16x8*)&Bh[wc + n * 16 + lr][lk * 8];
            fbl[n] = *(const bf16x8*)&Bl[wc + n * 16 + lr][lk * 8];
        }
        #pragma unroll
        for (int m = 0; m < 2; ++m)
            #pragma unroll
            for (int n = 0; n < 2; ++n) {
                acc[m][n] = __builtin_amdgcn_mfma_f32_16x16x32_bf16(fal[m], fbh[n], acc[m][n], 0, 0, 0);
                acc[m][n] = __builtin_amdgcn_mfma_f32_16x16x32_bf16(fah[m], fbl[n], acc[m][n], 0, 0, 0);
                acc[m][n] = __builtin_amdgcn_mfma_f32_16x16x32_bf16(fah[m], fbh[n], acc[m][n], 0, 0, 0);
            }
        __syncthreads();
    }
    #pragma unroll
    for (int m = 0; m < 2; ++m) {
        #pragma unroll
        for (int q = 0; q < 4; ++q) {
            int gr = r0 + wr + m * 16 + lk * 4 + q;
            if (gr >= M) continue;
            #pragma unroll
            for (int n = 0; n < 2; ++n) {
                int gc = c0 + wc + n * 16 + lr;
                float v = acc[m][n][q] + (bias ? bias[gc] : 0.f);
                if (act) v = tanhf(v);
                C[(long)gr * ldc + gc] = v;
            }
        }
    }
}

// split-bf16 GEMM with gathered concat A = [ent[sel[p]] | ci[g]]; K=1536, N=768
__global__ __launch_bounds__(256)
void k_gemm_split_cat(const float* __restrict__ ent, const float* __restrict__ ci,
                      const int* __restrict__ sel, const float* __restrict__ W,
                      const float* __restrict__ bias, float* __restrict__ C)
{
    __shared__ ushort Ah[64][40], Al[64][40], Bh[64][40], Bl[64][40];
    const int tid = threadIdx.x;
    const int r0 = blockIdx.y * 64, c0 = blockIdx.x * 64;
    const int w = tid >> 6, l = tid & 63, lr = l & 15, lk = l >> 4;
    const int wr = (w >> 1) * 32, wc = (w & 1) * 32;
    f32x4 acc[2][2];
    #pragma unroll
    for (int m = 0; m < 2; ++m)
        #pragma unroll
        for (int n = 0; n < 2; ++n) acc[m][n] = (f32x4){0.f, 0.f, 0.f, 0.f};

    const int ar  = tid >> 3;
    const int kq  = (tid & 7) * 4;
    const int bkk = tid >> 4;
    const int cc4 = (tid & 15) * 4;
    // per-thread row gather pointers (rows ar and ar+32)
    const float* pe[2]; const float* pc[2]; bool okr[2];
    #pragma unroll
    for (int s = 0; s < 2; ++s) {
        int gr = r0 + ar + s * 32;
        okr[s] = gr < Nn;
        int g = okr[s] ? gr : Nn - 1;
        int b = g / Pp, p = g % Pp;
        pe[s] = ent + ((long)b * NEe + sel[p]) * Dm;
        pc[s] = ci + (long)g * Dm;
    }
    const float4 z4 = make_float4(0.f, 0.f, 0.f, 0.f);

    for (int k0 = 0; k0 < 2 * Dm; k0 += 32) {
        #pragma unroll
        for (int s = 0; s < 2; ++s) {
            int r = ar + s * 32;
            int k = k0 + kq;
            const float* src = (k < Dm) ? (pe[s] + k) : (pc[s] + k - Dm);
            float4 v = okr[s] ? *(const float4*)src : z4;
            ushort h0, l0, h1, l1;
            split2(v.x, h0, l0); split2(v.y, h1, l1);
            *(uint*)&Ah[r][kq]     = (uint)h0 | ((uint)h1 << 16);
            *(uint*)&Al[r][kq]     = (uint)l0 | ((uint)l1 << 16);
            split2(v.z, h0, l0); split2(v.w, h1, l1);
            *(uint*)&Ah[r][kq + 2] = (uint)h0 | ((uint)h1 << 16);
            *(uint*)&Al[r][kq + 2] = (uint)l0 | ((uint)l1 << 16);
        }
        #pragma unroll
        for (int s = 0; s < 2; ++s) {
            int kk = bkk + s * 16;
            float4 v = *(const float4*)&W[(long)(k0 + kk) * Dm + c0 + cc4];
            ushort hh, ll;
            split2(v.x, hh, ll); Bh[cc4 + 0][kk] = hh; Bl[cc4 + 0][kk] = ll;
            split2(v.y, hh, ll); Bh[cc4 + 1][kk] = hh; Bl[cc4 + 1][kk] = ll;
            split2(v.z, hh, ll); Bh[cc4 + 2][kk] = hh; Bl[cc4 + 2][kk] = ll;
            split2(v.w, hh, ll); Bh[cc4 + 3][kk] = hh; Bl[cc4 + 3][kk] = ll;
        }
        __syncthreads();
        bf16x8 fah[2], fal[2], fbh[2], fbl[2];
        #pragma unroll
        for (int m = 0; m < 2; ++m) {
            fah[m] = *(const bf16x8*)&Ah[wr + m * 16 + lr][lk * 8];
            fal[m] = *(const bf16x8*)&Al[wr + m * 16 + lr][lk * 8];
        }
        #pragma unroll
        for (int n = 0; n < 2; ++n) {
            fbh[n] = *(const bf16x8*)&Bh[wc + n * 16 + lr][lk * 8];
            fbl[n] = *(const bf16x8*)&Bl[wc + n * 16 + lr][lk * 8];
        }
        #pragma unroll
        for (int m = 0; m < 2; ++m)
            #pragma unroll
            for (int n = 0; n < 2; ++n) {
                acc[m][n] = __builtin_amdgcn_mfma_f32_16x16x32_bf16(fal[m], fbh[n], acc[m][n], 0, 0, 0);
                acc[m][n] = __builtin_amdgcn_mfma_f32_16x16x32_bf16(fah[m], fbl[n], acc[m][n], 0, 0, 0);
                acc[m][n] = __builtin_amdgcn_mfma_f32_16x16x32_bf16(fah[m], fbh[n], acc[m][n], 0, 0, 0);
            }
        __syncthreads();
    }
    #pragma unroll
    for (int m = 0; m < 2; ++m) {
        #pragma unroll
        for (int q = 0; q < 4; ++q) {
            int gr = r0 + wr + m * 16 + lk * 4 + q;
            if (gr >= Nn) continue;
            #pragma unroll
            for (int n = 0; n < 2; ++n) {
                int gc = c0 + wc + n * 16 + lr;
                C[(long)gr * Dm + gc] = tanhf(acc[m][n][q] + bias[gc]);
            }
        }
    }
}

// Wbin [(h*64+i)*64+j][2] -> Wb2[h][j][i*2+o] f32
__global__ void k_wbinT(const float* __restrict__ W, float* __restrict__ out)
{
    int h = blockIdx.x;              // 0..11
    for (int idx = threadIdx.x; idx < 64 * 128; idx += 256) {
        int j = idx >> 7, io = idx & 127;
        int i = io >> 1, o = io & 1;
        out[(long)h * 64 * 128 + idx] = W[(((long)h * 64 + i) * 64 + j) * 2 + o];
    }
}

// out0[n][o] = bbin[o] + sum_{h,i} act1[n][h*64+i] * T[h][n][i*2+o]
// grid 552 blocks x 256 thr (4 waves, one n per wave)
__global__ void k_binred(const float* __restrict__ act1, const float* __restrict__ T,
                         const float* __restrict__ bias, float* __restrict__ out0)
{
    int w = threadIdx.x >> 6, l = threadIdx.x & 63;
    int n = blockIdx.x * 4 + w;
    if (n >= Nn) return;
    float a0 = 0.f, a1 = 0.f;
    #pragma unroll
    for (int h = 0; h < Hh; ++h) {
        float a = act1[(long)n * Dm + h * 64 + l];
        const float* t = T + ((long)(h * Nn + n)) * 128 + l * 2;
        a0 += a * t[0];
        a1 += a * t[1];
    }
    #pragma unroll
    for (int off = 32; off > 0; off >>= 1) {
        a0 += __shfl_down(a0, off);
        a1 += __shfl_down(a1, off);
    }
    if (l == 0) {
        out0[n * 2 + 0] = a0 + bias[0];
        out0[n * 2 + 1] = a1 + bias[1];
    }
}

// ---------- weight transpose + bf16 convert: out[N][K] <- in[K][N] ----------
__global__ void k_wT(const float* __restrict__ in, ushort* __restrict__ out, int K, int N)
{
    __shared__ float t[32][33];
    int k0 = blockIdx.y * 32, n0 = blockIdx.x * 32;
    int tx = threadIdx.x & 31, ty = threadIdx.x >> 5;   // 256 thr: ty 0..7
    #pragma unroll
    for (int s = 0; s < 4; ++s)
        t[ty + s * 8][tx] = in[(long)(k0 + ty + s * 8) * N + n0 + tx];
    __syncthreads();
    #pragma unroll
    for (int s = 0; s < 4; ++s)
        out[(long)(n0 + ty + s * 8) * K + k0 + tx] = f2b(t[tx][ty + s * 8]);
}

// Wrel [(h*64+i)*64+j][97] -> WrelB[(hi*112 + o)*64 + j] bf16 (o>=97 -> 0)
__global__ void k_wrelT(const float* __restrict__ W, ushort* __restrict__ out)
{
    int hi = blockIdx.x;            // 0..767
    for (int idx = threadIdx.x; idx < NPAD * 64; idx += 256) {
        int o = idx >> 6, j = idx & 63;
        float v = (o < Rr) ? W[((long)hi * 64 + j) * Rr + o] : 0.f;
        out[(long)hi * NPAD * 64 + idx] = f2b(v);
    }
}

// f32 -> bf16 flat convert (n4 = n/4)
__global__ void k_f2bf(const float* __restrict__ in, ushort* __restrict__ out, int n4)
{
    int i = blockIdx.x * 256 + threadIdx.x;
    if (i >= n4) return;
    float4 v = ((const float4*)in)[i];
    ushort4 o;
    o.x = f2b(v.x); o.y = f2b(v.y); o.z = f2b(v.z); o.w = f2b(v.w);
    ((ushort4*)out)[i] = o;
}

// ---------- bf16 MFMA GEMM: C[M][ldc] = A[M][K] @ Bt[N][K]^T ----------
__global__ __launch_bounds__(256)
void k_gemm_bf(const ushort* __restrict__ A, const ushort* __restrict__ Bt,
               float* __restrict__ C, int M, int N, int K, int ldc)
{
    __shared__ ushort As[128][40];
    __shared__ ushort Bs[128][40];
    const int tid = threadIdx.x;
    const int r0 = blockIdx.y * 128, c0 = blockIdx.x * 128;
    const int w = tid >> 6, l = tid & 63, lr = l & 15, lk = l >> 4;
    const int wr = (w >> 1) * 64, wc = (w & 1) * 64;
    f32x4 acc[4][4];
    #pragma unroll
    for (int m = 0; m < 4; ++m)
        #pragma unroll
        for (int n = 0; n < 4; ++n) acc[m][n] = (f32x4){0.f, 0.f, 0.f, 0.f};

    const int srow = tid >> 1, scb = (tid & 1) * 16;
    const uint4 z4 = make_uint4(0, 0, 0, 0);
    for (int k0 = 0; k0 < K; k0 += 32) {
        long gr = r0 + srow, gc = c0 + srow;
        const bool aok = gr < M, bok = gc < N;
        const ushort* ap = &A[gr * (long)K + k0 + scb];
        const ushort* bp = &Bt[gc * (long)K + k0 + scb];
        *(uint4*)&As[srow][scb]     = aok ? *(const uint4*)ap       : z4;
        *(uint4*)&As[srow][scb + 8] = aok ? *(const uint4*)(ap + 8) : z4;
        *(uint4*)&Bs[srow][scb]     = bok ? *(const uint4*)bp       : z4;
        *(uint4*)&Bs[srow][scb + 8] = bok ? *(const uint4*)(bp + 8) : z4;
        __syncthreads();
        bf16x8 af[4], bfr[4];
        #pragma unroll
        for (int m = 0; m < 4; ++m) af[m]  = *(const bf16x8*)&As[wr + m * 16 + lr][lk * 8];
        #pragma unroll
        for (int n = 0; n < 4; ++n) bfr[n] = *(const bf16x8*)&Bs[wc + n * 16 + lr][lk * 8];
        #pragma unroll
        for (int m = 0; m < 4; ++m)
            #pragma unroll
            for (int n = 0; n < 4; ++n)
                acc[m][n] = __builtin_amdgcn_mfma_f32_16x16x32_bf16(af[m], bfr[n], acc[m][n], 0, 0, 0);
        __syncthreads();
    }
    #pragma unroll
    for (int m = 0; m < 4; ++m) {
        #pragma unroll
        for (int q = 0; q < 4; ++q) {
            int gr = r0 + wr + m * 16 + lk * 4 + q;
            if (gr >= M) continue;
            #pragma unroll
            for (int n = 0; n < 4; ++n) {
                int gc = c0 + wc + n * 16 + lr;
                C[(long)gr * ldc + gc] = acc[m][n][q];
            }
        }
    }
}

// bf16 MFMA GEMM with virtual concat A = [nodes[sel[p]] | feat[g]], tanh epilogue
__global__ __launch_bounds__(256)
void k_gemm_bf_cat(const ushort* __restrict__ nodes, const ushort* __restrict__ feat,
                   const int* __restrict__ sel, const ushort* __restrict__ Bt,
                   const float* __restrict__ bias, float* __restrict__ C)
{
    __shared__ ushort As[128][40];
    __shared__ ushort Bs[128][40];
    const int tid = threadIdx.x;
    const int r0 = blockIdx.y * 128, c0 = blockIdx.x * 128;
    const int w = tid >> 6, l = tid & 63, lr = l & 15, lk = l >> 4;
    const int wr = (w >> 1) * 64, wc = (w & 1) * 64;
    f32x4 acc[4][4];
    #pragma unroll
    for (int m = 0; m < 4; ++m)
        #pragma unroll
        for (int n = 0; n < 4; ++n) acc[m][n] = (f32x4){0.f, 0.f, 0.f, 0.f};

    const int srow = tid >> 1, scb = (tid & 1) * 16;
    const int gra = r0 + srow;
    const bool a_ok = gra < Nn;
    const int grc = a_ok ? gra : Nn - 1;
    const int b = grc / Pp, p = grc % Pp;
    const ushort* pe = nodes + ((long)b * NEe + sel[p]) * Dm;
    const ushort* pc = feat + (long)grc * Dm;
    const int gc = c0 + srow;        // N=768, always < N
    const uint4 z4 = make_uint4(0, 0, 0, 0);
    for (int k0 = 0; k0 < 2 * Dm; k0 += 32) {
        const ushort* src = (k0 < Dm) ? (pe + k0 + scb) : (pc + (k0 - Dm) + scb);
        const ushort* bp  = &Bt[(long)gc * (2 * Dm) + k0 + scb];
        *(uint4*)&As[srow][scb]     = a_ok ? *(const uint4*)src       : z4;
        *(uint4*)&As[srow][scb + 8] = a_ok ? *(const uint4*)(src + 8) : z4;
        *(uint4*)&Bs[srow][scb]     = *(const uint4*)bp;
        *(uint4*)&Bs[srow][scb + 8] = *(const uint4*)(bp + 8);
        __syncthreads();
        bf16x8 af[4], bfr[4];
        #pragma unroll
        for (int m = 0; m < 4; ++m) af[m]  = *(const bf16x8*)&As[wr + m * 16 + lr][lk * 8];
        #pragma unroll
        for (int n = 0; n < 4; ++n) bfr[n] = *(const bf16x8*)&Bs[wc + n * 16 + lr][lk * 8];
        #pragma unroll
        for (int m = 0; m < 4; ++m)
            #pragma unroll
            for (int n = 0; n < 4; ++n)
                acc[m][n] = __builtin_amdgcn_mfma_f32_16x16x32_bf16(af[m], bfr[n], acc[m][n], 0, 0, 0);
        __syncthreads();
    }
    #pragma unroll
    for (int m = 0; m < 4; ++m) {
        #pragma unroll
        for (int q = 0; q < 4; ++q) {
            int gr = r0 + wr + m * 16 + lk * 4 + q;
            if (gr >= Nn) continue;
            #pragma unroll
            for (int n = 0; n < 4; ++n) {
                int gcc = c0 + wc + n * 16 + lr;
                C[(long)gr * Dm + gcc] = tanhf(acc[m][n][q] + bias[gcc]);
            }
        }
    }
}

// ---------- MFMA blockwise bilinear (relation head) ----------
__global__ __launch_bounds__(256)
void k_gbl_mfma(const float* __restrict__ Aact, const float* __restrict__ Cact,
                const ushort* __restrict__ Wt, float* __restrict__ part)
{
    const int h = blockIdx.y;
    const int r0 = blockIdx.x * 128;
    __shared__ float a_s[128][68];
    const int tid = threadIdx.x;
    {   // stage a-block [128][64]
        int row = tid >> 1, cb = (tid & 1) * 32;
        long gr = r0 + row;
        if (gr < Nn) {
            const float* ap = Aact + gr * Dm + h * BSz + cb;
            #pragma unroll
            for (int q = 0; q < 32; q += 4)
                *(float4*)&a_s[row][cb + q] = *(const float4*)&ap[q];
        } else {
            #pragma unroll
            for (int q = 0; q < 32; ++q) a_s[row][cb + q] = 0.f;
        }
    }
    __syncthreads();
    const int w = tid >> 6, l = tid & 63, lr = l & 15, lk = l >> 4;
    const int wr = w * 32;
    f32x4 acc[2][7];
    #pragma unroll
    for (int m = 0; m < 2; ++m)
        #pragma unroll
        for (int n = 0; n < 7; ++n) acc[m][n] = (f32x4){0.f, 0.f, 0.f, 0.f};

    const ushort* wbase = Wt + (long)h * 64 * NPAD * 64;   // [i][o][j]
    for (int j0 = 0; j0 < 64; j0 += 32) {
        float cc[2][8];
        #pragma unroll
        for (int m = 0; m < 2; ++m) {
            int crow = r0 + wr + m * 16 + lr;
            if (crow >= Nn) crow = Nn - 1;   // a=0 there anyway
            const float* cp = Cact + (long)crow * Dm + h * BSz + j0 + lk * 8;
            float4 clo = *(const float4*)cp;
            float4 chi = *(const float4*)(cp + 4);
            cc[m][0] = clo.x; cc[m][1] = clo.y; cc[m][2] = clo.z; cc[m][3] = clo.w;
            cc[m][4] = chi.x; cc[m][5] = chi.y; cc[m][6] = chi.z; cc[m][7] = chi.w;
        }
        for (int i = 0; i < 64; ++i) {
            bf16x8 bfr[7];
            const ushort* wp = wbase + (long)i * NPAD * 64 + j0 + lk * 8;
            #pragma unroll
            for (int n = 0; n < 7; ++n)
                bfr[n] = *(const bf16x8*)(wp + (long)(n * 16 + lr) * 64);
            #pragma unroll
            for (int m = 0; m < 2; ++m) {
                float av = a_s[wr + m * 16 + lr][i];
                bf16x8 af;
                #pragma unroll
                for (int q = 0; q < 8; ++q)
                    af[q] = (short)f2b(av * cc[m][q]);
                #pragma unroll
                for (int n = 0; n < 7; ++n)
                    acc[m][n] = __builtin_amdgcn_mfma_f32_16x16x32_bf16(af, bfr[n], acc[m][n], 0, 0, 0);
            }
        }
    }
    #pragma unroll
    for (int m = 0; m < 2; ++m) {
        #pragma unroll
        for (int q = 0; q < 4; ++q) {
            int gr = r0 + wr + m * 16 + lk * 4 + q;
            if (gr >= Nn) continue;
            #pragma unroll
            for (int n = 0; n < 7; ++n) {
                int o = n * 16 + lr;
                part[((long)h * Nn + gr) * NPAD + o] = acc[m][n][q];
            }
        }
    }
}

__global__ void k_rel_reduce(const float* __restrict__ part, const float* __restrict__ bias,
                             float* __restrict__ out)
{
    int idx = blockIdx.x * 256 + threadIdx.x;
    if (idx >= Nn * Rr) return;
    int n = idx / Rr, o = idx % Rr;
    float s = bias[o];
    #pragma unroll
    for (int h = 0; h < Hh; ++h) s += part[((long)h * Nn + n) * NPAD + o];
    out[idx] = s;
}

__global__ void k_mask(const float* __restrict__ bin, int* __restrict__ mask)
{
    int idx = blockIdx.x * 256 + threadIdx.x;
    if (idx >= Nn) return;
    mask[idx] = bin[idx * 2 + 1] > bin[idx * 2 + 0] ? 1 : 0;
}

// f_out[b,e,:] = (e<P ? fij[b,e] : 0) + ni[b,src] + nj[b,dst] + egat_b
__global__ void k_fassemble(const float* __restrict__ fij, const float* __restrict__ ni,
                            const float* __restrict__ nj, const float* __restrict__ eb,
                            const int* __restrict__ hts, float* __restrict__ fout, int ldn)
{
    int be = blockIdx.x; int b = be / Ee, e = be % Ee;
    int sn, dn; const float* fe = nullptr;
    if (e < Pp) { sn = hts[e]; dn = hts[Pp + e]; fe = fij + ((long)b * Pp + e) * Dm; }
    else        { sn = dn = e - Pp; }
    const float* nib = ni + ((long)b * NEe + sn) * ldn;
    const float* njb = nj + ((long)b * NEe + dn) * ldn;
    float* ob = fout + (long)be * Dm;
    for (int d = threadIdx.x; d < Dm; d += 256)
        ob[d] = (fe ? fe[d] : 0.f) + nib[d] + njb[d] + eb[d];
}

__global__ void k_score(const float* __restrict__ fout, const float* __restrict__ attp,
                        const int* __restrict__ mask, float* __restrict__ score)
{
    int idx = blockIdx.x * 256 + threadIdx.x;
    if (idx >= Bn * Ee * Hh) return;
    int h = idx % Hh; int be = idx / Hh; int b = be / Ee, e = be % Ee;
    const float* fb = fout + (long)be * Dm + h * BSz;
    const float* ap = attp + h * BSz;
    float s = 0.f;
    for (int j = 0; j < BSz; ++j) {
        float v = fb[j];
        float lr = v >= 0.f ? v : NEG_SLOPE * v;
        s += lr * ap[j];
    }
    bool ok = (e >= Pp) || (mask[b * Pp + e] != 0);
    score[idx] = ok ? s : -1e30f;
}

__global__ void k_segsoft(const float* __restrict__ score, float* __restrict__ attw)
{
    int idx = blockIdx.x * 256 + threadIdx.x;
    if (idx >= Bn * NEe * Hh) return;
    int h = idx % Hh; int bnn = idx / Hh; int b = bnn / NEe, n = bnn % NEe;
    float sc[NEe]; int es[NEe];
    float smax = -3e38f;
    #pragma unroll
    for (int hh = 0; hh < NEe; ++hh) {
        int e;
        if (hh == n) e = Pp + n;
        else         e = hh * (NEe - 1) + (n - (n > hh ? 1 : 0));
        float v = score[((long)b * Ee + e) * Hh + h];
        es[hh] = e; sc[hh] = v;
        smax = fmaxf(smax, v);
    }
    float den = 0.f;
    #pragma unroll
    for (int z = 0; z < NEe; ++z) { sc[z] = expf(sc[z] - smax); den += sc[z]; }
    float inv = 1.f / (den + 1e-20f);
    #pragma unroll
    for (int z = 0; z < NEe; ++z)
        attw[((long)b * Ee + es[z]) * Hh + h] = sc[z] * inv;
}

// node aggregation -> bf16 output (only consumer is the relation GEMM)
__global__ void k_nodeout_bf(const float* __restrict__ hsrcB, const float* __restrict__ attw,
                             ushort* __restrict__ nout, int ldn)
{
    int bnn = blockIdx.x; int b = bnn / NEe, n = bnn % NEe;
    for (int d = threadIdx.x; d < Dm; d += 256) {
        int h = d >> 6;
        float s = 0.f;
        #pragma unroll
        for (int hh = 0; hh < NEe; ++hh) {
            int e, sn;
            if (hh == n) { e = Pp + n; sn = n; }
            else         { e = hh * (NEe - 1) + (n - (n > hh ? 1 : 0)); sn = hh; }
            s += hsrcB[((long)b * NEe + sn) * ldn + d] * attw[((long)b * Ee + e) * Hh + h];
        }
        nout[(long)bnn * Dm + d] = f2b(s);
    }
}

// new_ci = mask ? f_out[:P] : ci  -> bf16 (only consumer is the relation GEMM)
__global__ void k_newci_bf(const float* __restrict__ fout, const float* __restrict__ ci,
                           const int* __restrict__ mask, ushort* __restrict__ out)
{
    int idx = blockIdx.x * 256 + threadIdx.x;
    if (idx >= Nn * Dm) return;
    int n = idx / Dm, d = idx % Dm;
    int b = n / Pp, p = n % Pp;
    out[idx] = f2b(mask[n] ? fout[((long)b * Ee + p) * Dm + d] : ci[idx]);
}

// ============================================================
extern "C" void kernel_launch(void* const* d_in, const int* in_sizes, int n_in,
                              void* d_out, int out_size, void* d_ws, size_t ws_size,
                              hipStream_t stream)
{
    const float* ctx   = (const float*)d_in[0];
    const float* att   = (const float*)d_in[1];
    const int*   mmap  = (const int*)d_in[2];
    const float* emap  = (const float*)d_in[3];
    const int*   hts   = (const int*)d_in[4];
    const float* Whb   = (const float*)d_in[5];
    const float* bhb   = (const float*)d_in[6];
    const float* Wtb   = (const float*)d_in[7];
    const float* btb   = (const float*)d_in[8];
    const float* Wbin  = (const float*)d_in[9];
    const float* bbin  = (const float*)d_in[10];
    const float* Wrel  = (const float*)d_in[11];
    const float* brel  = (const float*)d_in[12];
    const float* Wh    = (const float*)d_in[13];
    const float* bh    = (const float*)d_in[14];
    const float* Wt    = (const float*)d_in[15];
    const float* bt    = (const float*)d_in[16];
    const float* Wnode = (const float*)d_in[17];
    const float* Wni   = (const float*)d_in[18];
    const float* Wfij  = (const float*)d_in[19];
    const float* Wnj   = (const float*)d_in[20];
    const float* attp  = (const float*)d_in[21];
    const float* egatb = (const float*)d_in[22];

    float* out0 = (float*)d_out;            // bin_res [2208,2]
    float* out1 = out0 + (long)Nn * 2;      // relation_res [2208,97]

    // ---- workspace layout (float slots); total ~18.44M floats = 73.8 MB ----
    float* w = (float*)d_ws;
    size_t off = 0;
    auto alloc = [&](size_t nf) { float* p = w + off; off += nf; return p; };
    float* entity = alloc((size_t)Bn * NEe * Dm);          //    73,728
    float* curb   = alloc((size_t)Bn * Hh * NEe * Lq);     // 1,179,648  [T / partb alias]
    float* cab    = alloc((size_t)Bn * Pp * Lq);           // 2,260,992  [T / partb alias]
    float* cib    = alloc((size_t)Nn * Dm);                // 1,695,744
    float* act1   = alloc((size_t)Nn * Dm);                // 1,695,744
    float* act2   = alloc((size_t)Nn * Dm);                // 1,695,744
    float* fijb   = alloc((size_t)Nn * Dm);                // 1,695,744
    float* foutb  = alloc((size_t)Bn * Ee * Dm);           // 1,769,472
    float* comb   = alloc((size_t)Bn * NEe * 3 * Dm);      //   221,184  ni|nj|hsrc
    float* scoreb = alloc((size_t)Bn * Ee * Hh);           //    27,648
    float* attwb  = alloc((size_t)Bn * Ee * Hh);           //    27,648
    int*   maskb  = (int*)alloc(Nn);                       //     2,208
    ushort* entbf = (ushort*)alloc((size_t)Bn * NEe * Dm / 2);  // [noutbf alias]
    ushort* cibbf = (ushort*)alloc((size_t)Nn * Dm / 2);        // [newcibf alias]
    ushort* WTe   = (ushort*)alloc((size_t)3 * Dm * Dm / 2);    // [2304][768] bf16
    ushort* WfijT = (ushort*)alloc((size_t)Dm * Dm / 2);
    ushort* WhT   = (ushort*)alloc((size_t)Dm * 2 * Dm / 2);    // [768][1536]
    ushort* WtT   = (ushort*)alloc((size_t)Dm * 2 * Dm / 2);
    ushort* WrelB = (ushort*)alloc((size_t)Dm * NPAD * 64 / 2); // [768][112][64]
    float*  Wb2   = alloc((size_t)Hh * 64 * 128);               //    98,304 [h][j][i*2+o]
    // aliases (lifetimes disjoint, all within curb+cab = 3,440,640 floats):
    float*  Tb      = curb;            // [12][2208][128] = 3,391,488 (bin T-step)
    float*  partb   = curb;            // [12][2208][112] = 2,967,552 (rel bilinear, after T dead)
    ushort* noutbf  = entbf;           // entity-bf dead after comb gemm
    ushort* newcibf = cibbf;           // cib-bf dead after fij gemm

    // 0. weight conversions (input-only deps)
    k_wT<<<dim3(24, 24), 256, 0, stream>>>(Wni,   WTe,                 Dm, Dm);
    k_wT<<<dim3(24, 24), 256, 0, stream>>>(Wnj,   WTe + Dm * Dm,       Dm, Dm);
    k_wT<<<dim3(24, 24), 256, 0, stream>>>(Wnode, WTe + 2 * Dm * Dm,   Dm, Dm);
    k_wT<<<dim3(24, 24), 256, 0, stream>>>(Wfij,  WfijT,               Dm, Dm);
    k_wT<<<dim3(24, 48), 256, 0, stream>>>(Wh,    WhT,             2 * Dm, Dm);
    k_wT<<<dim3(24, 48), 256, 0, stream>>>(Wt,    WtT,             2 * Dm, Dm);
    k_wrelT<<<Dm, 256, 0, stream>>>(Wrel, WrelB);
    k_wbinT<<<Hh, 256, 0, stream>>>(Wbin, Wb2);

    // 1-4. pooling + ci (split-bf16 ~f32 accuracy)
    k_entity<<<Bn * NEe, 256, 0, stream>>>(ctx, mmap, emap, entity);
    k_cur<<<Bn * Hh * NEe, 256, 0, stream>>>(att, mmap, emap, curb);
    k_ca<<<Bn * Pp, 256, 0, stream>>>(curb, hts, cab);
    k_gemm_split<<<dim3(Dm / 64, (Pp + 63) / 64, Bn), 256, 0, stream>>>(
        cab, ctx, nullptr, cib, Pp, Dm, Lq, Lq, Dm, Dm,
        (long)Pp * Lq, (long)Lq * Dm, (long)Pp * Dm, 0);

    // 5-8. bin head (split-bf16, gathered concat) + T-step + reduce + mask
    k_gemm_split_cat<<<dim3(Dm / 64, (Nn + 63) / 64), 256, 0, stream>>>(entity, cib, hts,      Whb, bhb, act1);
    k_gemm_split_cat<<<dim3(Dm / 64, (Nn + 63) / 64), 256, 0, stream>>>(entity, cib, hts + Pp, Wtb, btb, act2);
    k_gemm_split<<<dim3(2, (Nn + 63) / 64, Hh), 256, 0, stream>>>(
        act2, Wb2, nullptr, Tb, Nn, 128, 64, Dm, 128, 128,
        64L, 64L * 128, (long)Nn * 128, 0);
    k_binred<<<Nn / 4, 256, 0, stream>>>(act1, Tb, bbin, out0);
    k_mask<<<(Nn + 255) / 256, 256, 0, stream>>>(out0, maskb);

    // 9-10. EGAT linears (fused, bf16 MFMA) + fij
    k_f2bf<<<(Bn * NEe * Dm / 4 + 255) / 256, 256, 0, stream>>>(entity, entbf, Bn * NEe * Dm / 4);
    k_gemm_bf<<<dim3(3 * Dm / 128, 1), 256, 0, stream>>>(entbf, WTe, comb, Bn * NEe, 3 * Dm, Dm, 3 * Dm);
    k_f2bf<<<(Nn * Dm / 4 + 255) / 256, 256, 0, stream>>>(cib, cibbf, Nn * Dm / 4);
    k_gemm_bf<<<dim3(Dm / 128, (Nn + 127) / 128), 256, 0, stream>>>(cibbf, WfijT, fijb, Nn, Dm, Dm, Dm);

    // 11-15. EGAT attention + new_ci (bf16 outputs)
    k_fassemble<<<Bn * Ee, 256, 0, stream>>>(fijb, comb, comb + Dm, egatb, hts, foutb, 3 * Dm);
    k_score<<<(Bn * Ee * Hh + 255) / 256, 256, 0, stream>>>(foutb, attp, maskb, scoreb);
    k_segsoft<<<(Bn * NEe * Hh + 255) / 256, 256, 0, stream>>>(scoreb, attwb);
    k_nodeout_bf<<<Bn * NEe, 256, 0, stream>>>(comb + 2 * Dm, attwb, noutbf, 3 * Dm);
    k_newci_bf<<<(Nn * Dm + 255) / 256, 256, 0, stream>>>(foutb, cib, maskb, newcibf);

    // 16-17. relation head GEMMs (bf16 MFMA, gathered concat, tanh)
    k_gemm_bf_cat<<<dim3(Dm / 128, (Nn + 127) / 128), 256, 0, stream>>>(noutbf, newcibf, hts,      WhT, bh, act1);
    k_gemm_bf_cat<<<dim3(Dm / 128, (Nn + 127) / 128), 256, 0, stream>>>(noutbf, newcibf, hts + Pp, WtT, bt, act2);

    // 18. relation bilinear (MFMA) -> out1
    k_gbl_mfma<<<dim3((Nn + 127) / 128, Hh), 256, 0, stream>>>(act1, act2, WrelB, partb);
    k_rel_reduce<<<(Nn * Rr + 255) / 256, 256, 0, stream>>>(partb, brel, out1);

    (void)in_sizes; (void)n_in; (void)out_size; (void)ws_size;
}